// Round 3
// baseline (174.730 us; speedup 1.0000x reference)
//
#include <hip/hip_runtime.h>
#include <hip/hip_bf16.h>

#define HEADS 8
#define DK 32
#define DV 64
#define DIM 256
#define NCTX 1024
#define NB 8
#define IDK 256
#define IDV 512
#define SCALE 0.17677669529663687f
#define INV_SCALE 5.656854249492381f
#define BN_EPS 1e-5f
#define THR 8.0f

typedef __bf16 bf16x8 __attribute__((ext_vector_type(8)));
typedef __bf16 bf16x4 __attribute__((ext_vector_type(4)));
typedef float f32x4 __attribute__((ext_vector_type(4)));

// ---------------- transpose x[b,c,n] f32 -> xT[b,n,c] bf16 ----------------
__global__ __launch_bounds__(256) void k_transpose(const float* __restrict__ x,
                                                   __bf16* __restrict__ xT) {
  __shared__ float t[64][65];
  int b = blockIdx.z, c0 = blockIdx.y * 64, n0 = blockIdx.x * 64;
  int col = threadIdx.x & 63, rb = threadIdx.x >> 6;
  const float* xp = x + ((size_t)b * DIM + c0) * NCTX + n0;
#pragma unroll
  for (int r = 0; r < 16; ++r) {
    int row = rb + 4 * r;
    t[row][col] = xp[(size_t)row * NCTX + col];
  }
  __syncthreads();
  __bf16* op = xT + ((size_t)b * NCTX + n0) * DIM + c0;
#pragma unroll
  for (int r = 0; r < 16; ++r) {
    int i = rb + 4 * r;
    op[(size_t)i * DIM + col] = (__bf16)t[col][i];
  }
}

// ---------------- Q/K projection: A=xT (M=i), B=W (N=o), K=c=256 ----------------
__global__ __launch_bounds__(256) void k_proj_qk(
    const __bf16* __restrict__ xT, const float* __restrict__ Wq, const float* __restrict__ Wk,
    const float* __restrict__ qg, const float* __restrict__ qb, const float* __restrict__ qm,
    const float* __restrict__ qv, const float* __restrict__ kg, const float* __restrict__ kb,
    const float* __restrict__ km, const float* __restrict__ kv,
    __bf16* __restrict__ Qws, __bf16* __restrict__ Kws) {
  int b = blockIdx.z;
  int iblk = blockIdx.x, oblk = blockIdx.y;  // oblk 0..7: 0-3 -> Q, 4-7 -> K
  int wave = threadIdx.x >> 6, lane = threadIdx.x & 63;
  int g = lane >> 4, l16 = lane & 15;
  bool isQ = oblk < 4;
  const float* W = isQ ? Wq : Wk;
  int obase = (oblk & 3) * 64;
  int i0w = iblk * 64 + wave * 16;
  const __bf16* xrow = xT + ((size_t)b * NCTX + i0w + l16) * DIM;
  f32x4 acc[4] = {};
#pragma unroll
  for (int kc = 0; kc < 8; ++kc) {
    int c = kc * 32 + g * 8;
    bf16x8 a = *reinterpret_cast<const bf16x8*>(xrow + c);
#pragma unroll
    for (int ot = 0; ot < 4; ++ot) {
      const float* wrow = W + (size_t)(obase + ot * 16 + l16) * DIM + c;
      bf16x8 bf;
#pragma unroll
      for (int j = 0; j < 8; ++j) bf[j] = (__bf16)wrow[j];
      acc[ot] = __builtin_amdgcn_mfma_f32_16x16x32_bf16(a, bf, acc[ot], 0, 0, 0);
    }
  }
  const float* gam = isQ ? qg : kg;
  const float* bet = isQ ? qb : kb;
  const float* mea = isQ ? qm : km;
  const float* var = isQ ? qv : kv;
  float sfac = isQ ? SCALE : 1.0f;
  __bf16* OWS = isQ ? Qws : Kws;
#pragma unroll
  for (int ot = 0; ot < 4; ++ot) {
    int o = obase + ot * 16 + l16;
    float sclr = gam[o] * rsqrtf(var[o] + BN_EPS);
    float scl = sclr * sfac;
    float bia = (bet[o] - mea[o] * sclr) * sfac;
    int h = o >> 5, d = o & 31;
#pragma unroll
    for (int r = 0; r < 4; ++r) {
      int i = i0w + g * 4 + r;
      float v = acc[ot][r] * scl + bia;
      OWS[(((size_t)b * HEADS + h) * NCTX + i) * DK + d] = (__bf16)v;
    }
  }
}

// ---------------- V projection: A=Wv (M=o=512), B=xT (N=i), K=c=256 ----------------
__global__ __launch_bounds__(256) void k_proj_v(
    const __bf16* __restrict__ xT, const float* __restrict__ Wv,
    const float* __restrict__ vg, const float* __restrict__ vb, const float* __restrict__ vm,
    const float* __restrict__ vv, __bf16* __restrict__ Vws) {
  int b = blockIdx.z, oblk = blockIdx.x, iblk = blockIdx.y;
  int wave = threadIdx.x >> 6, lane = threadIdx.x & 63;
  int g = lane >> 4, l16 = lane & 15;
  int o0w = oblk * 64 + wave * 16;
  int ibase = iblk * 64;
  const float* wrow = Wv + (size_t)(o0w + l16) * DIM;
  f32x4 acc[4] = {};
#pragma unroll
  for (int kc = 0; kc < 8; ++kc) {
    int c = kc * 32 + g * 8;
    bf16x8 af;
#pragma unroll
    for (int j = 0; j < 8; ++j) af[j] = (__bf16)wrow[c + j];
#pragma unroll
    for (int it = 0; it < 4; ++it) {
      bf16x8 bf = *reinterpret_cast<const bf16x8*>(
          xT + ((size_t)b * NCTX + ibase + it * 16 + l16) * DIM + c);
      acc[it] = __builtin_amdgcn_mfma_f32_16x16x32_bf16(af, bf, acc[it], 0, 0, 0);
    }
  }
#pragma unroll
  for (int r = 0; r < 4; ++r) {
    int o = o0w + g * 4 + r;
    float sclr = vg[o] * rsqrtf(vv[o] + BN_EPS);
    float bia = vb[o] - vm[o] * sclr;
#pragma unroll
    for (int it = 0; it < 4; ++it) {
      int i = ibase + it * 16 + l16;
      Vws[((size_t)b * IDV + o) * NCTX + i] = (__bf16)(acc[it][r] * sclr + bia);
    }
  }
}

// ---------------- attention: swapped QK^T + defer-max + reg-prefetch pipeline ----
// 1 block = (b,h) x 64 rows; wave owns 16 rows; lane owns ONE q-row (i = l16).
// K(t+1)/V(t+1) fragments prefetched into registers during iteration t.
// Bias via mirrored LDS table T[o] = pe[|o-1023|]: per-lane indices contiguous.
__global__ __launch_bounds__(256, 4) void k_attn(
    const __bf16* __restrict__ Qws, const __bf16* __restrict__ Kws,
    const __bf16* __restrict__ Vws, const float* __restrict__ pos_emb,
    __bf16* __restrict__ G) {
  // XCD-aware swizzle: each XCD gets 128 consecutive work ids (8 full bh groups)
  int flat = blockIdx.x + (blockIdx.y << 4);      // 0..1023
  int swz = (flat & 7) * 128 + (flat >> 3);
  int iblk = swz & 15, bh = swz >> 4;
  int b = bh >> 3, h = bh & 7;
  int wave = threadIdx.x >> 6, lane = threadIdx.x & 63;
  int g = lane >> 4, l16 = lane & 15;
  int g4 = g * 4;
  __shared__ float T[2047];
  __shared__ __align__(16) __bf16 plds[4][16][40];
  for (int o = threadIdx.x; o < 2047; o += 256) {
    int d = o - 1023; d = d < 0 ? -d : d;
    T[o] = pos_emb[(size_t)d * HEADS + h] * INV_SCALE;
  }
  __syncthreads();

  int i0w = iblk * 64 + wave * 16;
  int irow = i0w + l16;  // this lane's q-row
  const __bf16* qbase = Qws + (size_t)bh * NCTX * DK;
  const __bf16* kbase = Kws + (size_t)bh * NCTX * DK;
  const __bf16* vbase = Vws + ((size_t)b * IDV + h * DV) * NCTX;
  bf16x8 qfrag = *reinterpret_cast<const bf16x8*>(qbase + (size_t)irow * DK + g * 8);

  f32x4 acc[4] = {};
  float m = -1e30f, s = 0.0f;
  int tb = irow - g4 + 1023;  // bias table index base

  // prefetch chunk 0
  const __bf16* kp = kbase + (size_t)l16 * DK + g * 8;
  const __bf16* vp = vbase + (size_t)l16 * NCTX + g * 8;
  bf16x8 kf0 = *reinterpret_cast<const bf16x8*>(kp);
  bf16x8 kf1 = *reinterpret_cast<const bf16x8*>(kp + 16 * DK);
  bf16x8 vf0 = *reinterpret_cast<const bf16x8*>(vp);
  bf16x8 vf1 = *reinterpret_cast<const bf16x8*>(vp + 16 * NCTX);
  bf16x8 vf2 = *reinterpret_cast<const bf16x8*>(vp + 32 * NCTX);
  bf16x8 vf3 = *reinterpret_cast<const bf16x8*>(vp + 48 * NCTX);

  for (int j0 = 0; j0 < NCTX; j0 += 32) {
    // issue next-chunk loads (wraps to 0 on last iter: in-bounds, unused)
    int jn = (j0 + 32) & (NCTX - 1);
    const __bf16* kpn = kbase + (size_t)(jn + l16) * DK + g * 8;
    const __bf16* vpn = vbase + (size_t)l16 * NCTX + jn + g * 8;
    bf16x8 nkf0 = *reinterpret_cast<const bf16x8*>(kpn);
    bf16x8 nkf1 = *reinterpret_cast<const bf16x8*>(kpn + 16 * DK);
    bf16x8 nvf0 = *reinterpret_cast<const bf16x8*>(vpn);
    bf16x8 nvf1 = *reinterpret_cast<const bf16x8*>(vpn + 16 * NCTX);
    bf16x8 nvf2 = *reinterpret_cast<const bf16x8*>(vpn + 32 * NCTX);
    bf16x8 nvf3 = *reinterpret_cast<const bf16x8*>(vpn + 48 * NCTX);

    f32x4 z = {};
    f32x4 S0 = __builtin_amdgcn_mfma_f32_16x16x32_bf16(kf0, qfrag, z, 0, 0, 0);
    f32x4 S1 = __builtin_amdgcn_mfma_f32_16x16x32_bf16(kf1, qfrag, z, 0, 0, 0);

    // bias: lane's 4 indices per tile are consecutive (descending) in T
    const float* t0 = &T[tb - j0 - 3];   // tile0: T[tb-j0-r] = t0[3-r]
    const float* t1 = t0 - 16;           // tile1
    float sv[8];
#pragma unroll
    for (int r = 0; r < 4; ++r) {
      sv[r] = S0[r] + t0[3 - r];
      sv[r + 4] = S1[r] + t1[3 - r];
    }
    float pmax = fmaxf(fmaxf(fmaxf(sv[0], sv[1]), fmaxf(sv[2], sv[3])),
                       fmaxf(fmaxf(sv[4], sv[5]), fmaxf(sv[6], sv[7])));
    if (__any(pmax > m + THR)) {  // rare after first chunk
      float mx = fmaxf(pmax, __shfl_xor(pmax, 16));
      mx = fmaxf(mx, __shfl_xor(mx, 32));
      float mnew = fmaxf(m, mx);
      float corr = __expf(m - mnew);
      s *= corr;
      m = mnew;
#pragma unroll
      for (int r = 0; r < 4; ++r) {
        float c = __shfl(corr, (lane & 48) | (g4 + r));
        acc[0][r] *= c; acc[1][r] *= c; acc[2][r] *= c; acc[3][r] *= c;
      }
    }
    float e[8];
#pragma unroll
    for (int k = 0; k < 8; ++k) e[k] = __expf(sv[k] - m);
    s += ((e[0] + e[1]) + (e[2] + e[3])) + ((e[4] + e[5]) + (e[6] + e[7]));
    // P -> LDS: lane writes its own row, 2x packed b64
    bf16x4 pk0, pk1;
#pragma unroll
    for (int r = 0; r < 4; ++r) { pk0[r] = (__bf16)e[r]; pk1[r] = (__bf16)e[r + 4]; }
    *reinterpret_cast<bf16x4*>(&plds[wave][l16][g4]) = pk0;
    *reinterpret_cast<bf16x4*>(&plds[wave][l16][16 + g4]) = pk1;
    bf16x8 pfrag = *reinterpret_cast<const bf16x8*>(&plds[wave][l16][g * 8]);
    acc[0] = __builtin_amdgcn_mfma_f32_16x16x32_bf16(pfrag, vf0, acc[0], 0, 0, 0);
    acc[1] = __builtin_amdgcn_mfma_f32_16x16x32_bf16(pfrag, vf1, acc[1], 0, 0, 0);
    acc[2] = __builtin_amdgcn_mfma_f32_16x16x32_bf16(pfrag, vf2, acc[2], 0, 0, 0);
    acc[3] = __builtin_amdgcn_mfma_f32_16x16x32_bf16(pfrag, vf3, acc[3], 0, 0, 0);
    // rotate pipeline registers
    kf0 = nkf0; kf1 = nkf1;
    vf0 = nvf0; vf1 = nvf1; vf2 = nvf2; vf3 = nvf3;
  }
  // epilogue: single sum-tree across the row's 4 g-lanes, then /s, gelu, store
  s += __shfl_xor(s, 16);
  s += __shfl_xor(s, 32);
  float inv = 1.0f / s;  // valid for row irow (= l16 slot)
  float invr[4];
#pragma unroll
  for (int r = 0; r < 4; ++r) invr[r] = __shfl(inv, (lane & 48) | (g4 + r));
  __bf16* gbase = G + (size_t)b * NCTX * IDV;
#pragma unroll
  for (int dt = 0; dt < 4; ++dt) {
    int cch = h * DV + dt * 16 + l16;
#pragma unroll
    for (int r = 0; r < 4; ++r) {
      float v = acc[dt][r] * invr[r];
      float ge = 0.5f * v * (1.0f + erff(v * 0.70710678118654752f));
      gbase[(size_t)(i0w + g4 + r) * IDV + cch] = (__bf16)ge;
    }
  }
}

// ---------------- out projection: A=Wo (M=o=256), B=G (N=i), K=c=512 ----------------
__global__ __launch_bounds__(256) void k_out(
    const __bf16* __restrict__ G, const float* __restrict__ Wo, const float* __restrict__ bo,
    const float* __restrict__ og, const float* __restrict__ ob, const float* __restrict__ om,
    const float* __restrict__ ov, float* __restrict__ out) {
  int b = blockIdx.z, oblk = blockIdx.x, iblk = blockIdx.y;
  int wave = threadIdx.x >> 6, lane = threadIdx.x & 63;
  int g = lane >> 4, l16 = lane & 15;
  int o0w = oblk * 64 + wave * 16;
  int ibase = iblk * 64;
  const float* wrow = Wo + (size_t)(o0w + l16) * IDV;
  const __bf16* gb = G + (size_t)b * NCTX * IDV;
  f32x4 acc[4] = {};
#pragma unroll
  for (int kc = 0; kc < 16; ++kc) {
    int c = kc * 32 + g * 8;
    bf16x8 af;
#pragma unroll
    for (int j = 0; j < 8; ++j) af[j] = (__bf16)wrow[c + j];
#pragma unroll
    for (int it = 0; it < 4; ++it) {
      bf16x8 bf = *reinterpret_cast<const bf16x8*>(
          gb + (size_t)(ibase + it * 16 + l16) * IDV + c);
      acc[it] = __builtin_amdgcn_mfma_f32_16x16x32_bf16(af, bf, acc[it], 0, 0, 0);
    }
  }
#pragma unroll
  for (int r = 0; r < 4; ++r) {
    int o = o0w + g * 4 + r;
    float sclr = og[o] * rsqrtf(ov[o] + BN_EPS);
    float bia = (bo[o] - om[o]) * sclr + ob[o];
#pragma unroll
    for (int it = 0; it < 4; ++it) {
      int i = ibase + it * 16 + l16;
      out[((size_t)b * DIM + o) * NCTX + i] = acc[it][r] * sclr + bia;
    }
  }
}

extern "C" void kernel_launch(void* const* d_in, const int* in_sizes, int n_in,
                              void* d_out, int out_size, void* d_ws, size_t ws_size,
                              hipStream_t stream) {
  const float* x  = (const float*)d_in[0];
  const float* Wq = (const float*)d_in[1];
  const float* Wk = (const float*)d_in[2];
  const float* Wv = (const float*)d_in[3];
  const float* Wo = (const float*)d_in[4];
  const float* bo = (const float*)d_in[5];
  const float* pe = (const float*)d_in[6];
  const float* qg = (const float*)d_in[7];
  const float* qb = (const float*)d_in[8];
  const float* qm = (const float*)d_in[9];
  const float* qv = (const float*)d_in[10];
  const float* kg = (const float*)d_in[11];
  const float* kb = (const float*)d_in[12];
  const float* km = (const float*)d_in[13];
  const float* kv = (const float*)d_in[14];
  const float* vg = (const float*)d_in[15];
  const float* vb = (const float*)d_in[16];
  const float* vm = (const float*)d_in[17];
  const float* vv = (const float*)d_in[18];
  const float* og = (const float*)d_in[19];
  const float* ob = (const float*)d_in[20];
  const float* om = (const float*)d_in[21];
  const float* ov = (const float*)d_in[22];

  char* ws = (char*)d_ws;
  __bf16* xT = (__bf16*)(ws);                       // 4 MB
  __bf16* Q  = (__bf16*)(ws + (4ull << 20));        // 4 MB
  __bf16* K  = (__bf16*)(ws + (8ull << 20));        // 4 MB
  __bf16* V  = (__bf16*)(ws + (12ull << 20));       // 8 MB
  __bf16* G  = (__bf16*)(ws + (20ull << 20));       // 8 MB
  float* out = (float*)d_out;

  k_transpose<<<dim3(16, 4, NB), 256, 0, stream>>>(x, xT);
  k_proj_qk<<<dim3(16, 8, NB), 256, 0, stream>>>(xT, Wq, Wk, qg, qb, qm, qv,
                                                 kg, kb, km, kv, Q, K);
  k_proj_v<<<dim3(8, 16, NB), 256, 0, stream>>>(xT, Wv, vg, vb, vm, vv, V);
  k_attn<<<dim3(16, 64), 256, 0, stream>>>(Q, K, V, pe, G);
  k_out<<<dim3(4, 16, NB), 256, 0, stream>>>(G, Wo, bo, og, ob, om, ov, out);
}

// Round 4
// 110.190 us; speedup vs baseline: 1.5857x; 1.5857x over previous
//
#include <hip/hip_runtime.h>
#include <hip/hip_bf16.h>

#define HEADS 8
#define DK 32
#define DV 64
#define DIM 256
#define NCTX 1024
#define NB 8
#define IDK 256
#define IDV 512
#define SCALE 0.17677669529663687f
#define INV_SCALE 5.656854249492381f
#define BN_EPS 1e-5f
#define THR 8.0f

typedef __bf16 bf16x8 __attribute__((ext_vector_type(8)));
typedef __bf16 bf16x4 __attribute__((ext_vector_type(4)));
typedef float f32x4 __attribute__((ext_vector_type(4)));

// ---------------- prep: fold BN (+SCALE) into bf16 weights + bias ----------------
// WB: WqB[65536] | WkB[65536] | WvB[131072] | WoB[131072]   (bf16)
// BB: bq[256] | bk[256] | bv[512] | bo2[256]                 (f32)
__global__ __launch_bounds__(256) void k_prep(
    const float* __restrict__ Wq, const float* __restrict__ Wk,
    const float* __restrict__ Wv, const float* __restrict__ Wo,
    const float* __restrict__ bo,
    const float* __restrict__ qg, const float* __restrict__ qb,
    const float* __restrict__ qm, const float* __restrict__ qv,
    const float* __restrict__ kg, const float* __restrict__ kb,
    const float* __restrict__ km, const float* __restrict__ kv,
    const float* __restrict__ vg, const float* __restrict__ vb,
    const float* __restrict__ vm, const float* __restrict__ vv,
    const float* __restrict__ og, const float* __restrict__ ob,
    const float* __restrict__ om, const float* __restrict__ ov,
    __bf16* __restrict__ WB, float* __restrict__ BB) {
  int idx = blockIdx.x * 256 + threadIdx.x;
  if (idx < 65536) {
    int o = idx >> 8;
    float scl = qg[o] * rsqrtf(qv[o] + BN_EPS) * SCALE;
    WB[idx] = (__bf16)(Wq[idx] * scl);
  } else if (idx < 131072) {
    int i = idx - 65536, o = i >> 8;
    float scl = kg[o] * rsqrtf(kv[o] + BN_EPS);
    WB[idx] = (__bf16)(Wk[i] * scl);
  } else if (idx < 262144) {
    int i = idx - 131072, o = i >> 8;
    float scl = vg[o] * rsqrtf(vv[o] + BN_EPS);
    WB[idx] = (__bf16)(Wv[i] * scl);
  } else if (idx < 393216) {
    int i = idx - 262144, o = i >> 9;
    float scl = og[o] * rsqrtf(ov[o] + BN_EPS);
    WB[idx] = (__bf16)(Wo[i] * scl);
  } else if (idx < 394496) {
    int i = idx - 393216;
    if (i < 256) {
      float sc = qg[i] * rsqrtf(qv[i] + BN_EPS);
      BB[i] = (qb[i] - qm[i] * sc) * SCALE;
    } else if (i < 512) {
      int o = i - 256;
      float sc = kg[o] * rsqrtf(kv[o] + BN_EPS);
      BB[i] = kb[o] - km[o] * sc;
    } else if (i < 1024) {
      int o = i - 512;
      float sc = vg[o] * rsqrtf(vv[o] + BN_EPS);
      BB[i] = vb[o] - vm[o] * sc;
    } else {
      int o = i - 1024;
      float sc = og[o] * rsqrtf(ov[o] + BN_EPS);
      BB[i] = (bo[o] - om[o]) * sc + ob[o];
    }
  }
}

// ---------------- transpose x[b,c,n] f32 -> xT[b,n,c] bf16 ----------------
__global__ __launch_bounds__(256) void k_transpose(const float* __restrict__ x,
                                                   __bf16* __restrict__ xT) {
  __shared__ float t[64][65];
  int b = blockIdx.z, c0 = blockIdx.y * 64, n0 = blockIdx.x * 64;
  int col = threadIdx.x & 63, rb = threadIdx.x >> 6;
  const float* xp = x + ((size_t)b * DIM + c0) * NCTX + n0;
#pragma unroll
  for (int r = 0; r < 16; ++r) {
    int row = rb + 4 * r;
    t[row][col] = xp[(size_t)row * NCTX + col];
  }
  __syncthreads();
  __bf16* op = xT + ((size_t)b * NCTX + n0) * DIM + c0;
#pragma unroll
  for (int r = 0; r < 16; ++r) {
    int i = rb + 4 * r;
    op[(size_t)i * DIM + col] = (__bf16)t[col][i];
  }
}

// ---------------- Q/K projection (prepped bf16 weights) ----------------
__global__ __launch_bounds__(256) void k_proj_qk(
    const __bf16* __restrict__ xT, const __bf16* __restrict__ WB,
    const float* __restrict__ BB, __bf16* __restrict__ Qws, __bf16* __restrict__ Kws) {
  int b = blockIdx.z;
  int iblk = blockIdx.x, oblk = blockIdx.y;  // 0-3 -> Q, 4-7 -> K
  int wave = threadIdx.x >> 6, lane = threadIdx.x & 63;
  int g = lane >> 4, l16 = lane & 15;
  bool isQ = oblk < 4;
  const __bf16* W = isQ ? WB : WB + 65536;
  const float* bias = isQ ? BB : BB + 256;
  int obase = (oblk & 3) * 64;
  int i0w = iblk * 64 + wave * 16;
  const __bf16* xrow = xT + ((size_t)b * NCTX + i0w + l16) * DIM;
  f32x4 acc[4] = {};
#pragma unroll
  for (int kc = 0; kc < 8; ++kc) {
    int c = kc * 32 + g * 8;
    bf16x8 a = *reinterpret_cast<const bf16x8*>(xrow + c);
#pragma unroll
    for (int ot = 0; ot < 4; ++ot) {
      bf16x8 bf = *reinterpret_cast<const bf16x8*>(W + (size_t)(obase + ot * 16 + l16) * DIM + c);
      acc[ot] = __builtin_amdgcn_mfma_f32_16x16x32_bf16(a, bf, acc[ot], 0, 0, 0);
    }
  }
  __bf16* OWS = isQ ? Qws : Kws;
#pragma unroll
  for (int ot = 0; ot < 4; ++ot) {
    int o = obase + ot * 16 + l16;
    float bia = bias[o];
    int h = o >> 5, d = o & 31;
#pragma unroll
    for (int r = 0; r < 4; ++r) {
      int i = i0w + g * 4 + r;
      OWS[(((size_t)b * HEADS + h) * NCTX + i) * DK + d] = (__bf16)(acc[ot][r] + bia);
    }
  }
}

// ---------------- V projection (prepped bf16 weights) ----------------
__global__ __launch_bounds__(256) void k_proj_v(
    const __bf16* __restrict__ xT, const __bf16* __restrict__ WB,
    const float* __restrict__ BB, __bf16* __restrict__ Vws) {
  int b = blockIdx.z, oblk = blockIdx.x, iblk = blockIdx.y;
  int wave = threadIdx.x >> 6, lane = threadIdx.x & 63;
  int g = lane >> 4, l16 = lane & 15;
  int o0w = oblk * 64 + wave * 16;
  int ibase = iblk * 64;
  const __bf16* WvB = WB + 131072;
  const float* bv = BB + 512;
  const __bf16* wrow = WvB + (size_t)(o0w + l16) * DIM;
  f32x4 acc[4] = {};
#pragma unroll
  for (int kc = 0; kc < 8; ++kc) {
    int c = kc * 32 + g * 8;
    bf16x8 af = *reinterpret_cast<const bf16x8*>(wrow + c);
#pragma unroll
    for (int it = 0; it < 4; ++it) {
      bf16x8 bf = *reinterpret_cast<const bf16x8*>(
          xT + ((size_t)b * NCTX + ibase + it * 16 + l16) * DIM + c);
      acc[it] = __builtin_amdgcn_mfma_f32_16x16x32_bf16(af, bf, acc[it], 0, 0, 0);
    }
  }
#pragma unroll
  for (int r = 0; r < 4; ++r) {
    int o = o0w + g * 4 + r;
    float bia = bv[o];
#pragma unroll
    for (int it = 0; it < 4; ++it) {
      int i = ibase + it * 16 + l16;
      Vws[((size_t)b * IDV + o) * NCTX + i] = (__bf16)(acc[it][r] + bia);
    }
  }
}

// ---------------- attention: KVBLK=64, block-cooperative padded-LDS staging ------
// Single LDS buffer; T14 split: loads for tile t+1 issued AFTER barrier B of
// iter t -> in flight across the whole compute phase, drained at next A barrier.
__global__ __launch_bounds__(256, 4) void k_attn(
    const __bf16* __restrict__ Qws, const __bf16* __restrict__ Kws,
    const __bf16* __restrict__ Vws, const float* __restrict__ pos_emb,
    __bf16* __restrict__ G) {
  int flat = blockIdx.x + (blockIdx.y << 4);
  int swz = (flat & 7) * 128 + (flat >> 3);   // XCD-aware: 128 consecutive ids/XCD
  int iblk = swz & 15, bh = swz >> 4;
  int b = bh >> 3, h = bh & 7;
  int tid = threadIdx.x;
  int wave = tid >> 6, lane = tid & 63;
  int g = lane >> 4, l16 = lane & 15, g4 = g * 4;

  __shared__ float T[1087];                        // bias slice for this block
  __shared__ __align__(16) __bf16 Klds[64][40];    // 80B rows -> ~2-way reads
  __shared__ __align__(16) __bf16 Vlds[64][72];    // 144B rows -> ~2-way reads
  __shared__ __align__(16) __bf16 plds[4][16][72];

  int i0b = iblk * 64;
  for (int k = tid; k < 1087; k += 256) {
    int d = i0b + k - 1023; d = d < 0 ? -d : d;
    T[k] = pos_emb[(size_t)d * HEADS + h] * INV_SCALE;
  }

  int i0w = i0b + wave * 16;
  int irow = i0w + l16;
  const __bf16* qbase = Qws + (size_t)bh * NCTX * DK;
  const __bf16* kbase = Kws + (size_t)bh * NCTX * DK;
  const __bf16* vbase = Vws + ((size_t)b * IDV + h * DV) * NCTX;
  bf16x8 qfrag = *reinterpret_cast<const bf16x8*>(qbase + (size_t)irow * DK + g * 8);

  // staging mapping: thread -> K row r_, chunk c8; V row r_, chunks c8, c8+32
  int r_ = tid >> 2, c8 = (tid & 3) * 8;
  const __bf16* kg_ = kbase + (size_t)r_ * DK + c8;
  const __bf16* vg_ = vbase + (size_t)r_ * NCTX + c8;

  // prologue: tile 0 into regs
  bf16x8 rk = *reinterpret_cast<const bf16x8*>(kg_);
  bf16x8 rv0 = *reinterpret_cast<const bf16x8*>(vg_);
  bf16x8 rv1 = *reinterpret_cast<const bf16x8*>(vg_ + 32);

  f32x4 acc[4] = {};
  float m = -1e30f, s = 0.0f;
  int tb = wave * 16 + l16 + 1023;   // T index base (block-local)

  for (int it = 0; it < 16; ++it) {
    int j0 = it * 64;
    __syncthreads();  // A: previous compute done with LDS (drains prefetch loads)
    *reinterpret_cast<bf16x8*>(&Klds[r_][c8]) = rk;
    *reinterpret_cast<bf16x8*>(&Vlds[r_][c8]) = rv0;
    *reinterpret_cast<bf16x8*>(&Vlds[r_][c8 + 32]) = rv1;
    __syncthreads();  // B: tile visible
    // issue next-tile loads AFTER B: in flight across this whole compute phase
    int jn = (j0 + 64) & (NCTX - 1);
    rk = *reinterpret_cast<const bf16x8*>(kg_ + (size_t)jn * DK);
    rv0 = *reinterpret_cast<const bf16x8*>(vg_ + jn);
    rv1 = *reinterpret_cast<const bf16x8*>(vg_ + jn + 32);

    // S^T tiles: A = K rows (local j), B = Q
    f32x4 z = {};
    f32x4 S0 = __builtin_amdgcn_mfma_f32_16x16x32_bf16(
        *reinterpret_cast<const bf16x8*>(&Klds[l16][g * 8]), qfrag, z, 0, 0, 0);
    f32x4 S1 = __builtin_amdgcn_mfma_f32_16x16x32_bf16(
        *reinterpret_cast<const bf16x8*>(&Klds[16 + l16][g * 8]), qfrag, z, 0, 0, 0);
    f32x4 S2 = __builtin_amdgcn_mfma_f32_16x16x32_bf16(
        *reinterpret_cast<const bf16x8*>(&Klds[32 + l16][g * 8]), qfrag, z, 0, 0, 0);
    f32x4 S3 = __builtin_amdgcn_mfma_f32_16x16x32_bf16(
        *reinterpret_cast<const bf16x8*>(&Klds[48 + l16][g * 8]), qfrag, z, 0, 0, 0);

    // bias + scores; lane's j = j0 + jt*16 + g4 + rr
    float sv[16];
    int ib = tb - j0 - g4;
#pragma unroll
    for (int rr = 0; rr < 4; ++rr) {
      sv[rr] = S0[rr] + T[ib - rr];
      sv[4 + rr] = S1[rr] + T[ib - 16 - rr];
      sv[8 + rr] = S2[rr] + T[ib - 32 - rr];
      sv[12 + rr] = S3[rr] + T[ib - 48 - rr];
    }
    float pmax = fmaxf(fmaxf(fmaxf(sv[0], sv[1]), fmaxf(sv[2], sv[3])),
                       fmaxf(fmaxf(sv[4], sv[5]), fmaxf(sv[6], sv[7])));
    pmax = fmaxf(pmax, fmaxf(fmaxf(fmaxf(sv[8], sv[9]), fmaxf(sv[10], sv[11])),
                             fmaxf(fmaxf(sv[12], sv[13]), fmaxf(sv[14], sv[15]))));
    if (__any(pmax > m + THR)) {  // rare after first tile; m stays row-uniform
      float mx = fmaxf(pmax, __shfl_xor(pmax, 16));
      mx = fmaxf(mx, __shfl_xor(mx, 32));
      float mnew = fmaxf(m, mx);
      float corr = __expf(m - mnew);
      s *= corr;
      m = mnew;
#pragma unroll
      for (int r = 0; r < 4; ++r) {
        float c = __shfl(corr, (lane & 48) | (g4 + r));
        acc[0][r] *= c; acc[1][r] *= c; acc[2][r] *= c; acc[3][r] *= c;
      }
    }
    float e[16];
#pragma unroll
    for (int k = 0; k < 16; ++k) e[k] = __expf(sv[k] - m);
    float ps = 0.0f;
#pragma unroll
    for (int k = 0; k < 16; ++k) ps += e[k];
    s += ps;
    // P -> padded LDS (lane writes own row), then A-frags for PV
#pragma unroll
    for (int jt = 0; jt < 4; ++jt) {
      bf16x4 pk;
#pragma unroll
      for (int rr = 0; rr < 4; ++rr) pk[rr] = (__bf16)e[jt * 4 + rr];
      *reinterpret_cast<bf16x4*>(&plds[wave][l16][jt * 16 + g4]) = pk;
    }
    bf16x8 pf0 = *reinterpret_cast<const bf16x8*>(&plds[wave][l16][g * 8]);
    bf16x8 pf1 = *reinterpret_cast<const bf16x8*>(&plds[wave][l16][32 + g * 8]);
#pragma unroll
    for (int dt = 0; dt < 4; ++dt) {
      acc[dt] = __builtin_amdgcn_mfma_f32_16x16x32_bf16(
          pf0, *reinterpret_cast<const bf16x8*>(&Vlds[dt * 16 + l16][g * 8]),
          acc[dt], 0, 0, 0);
      acc[dt] = __builtin_amdgcn_mfma_f32_16x16x32_bf16(
          pf1, *reinterpret_cast<const bf16x8*>(&Vlds[dt * 16 + l16][32 + g * 8]),
          acc[dt], 0, 0, 0);
    }
  }
  // epilogue: row sums across g-lanes, /s, exact gelu, store
  s += __shfl_xor(s, 16);
  s += __shfl_xor(s, 32);
  float inv = 1.0f / s;
  float invr[4];
#pragma unroll
  for (int r = 0; r < 4; ++r) invr[r] = __shfl(inv, (lane & 48) | (g4 + r));
  __bf16* gbase = G + (size_t)b * NCTX * IDV;
#pragma unroll
  for (int dt = 0; dt < 4; ++dt) {
    int cch = h * DV + dt * 16 + l16;
#pragma unroll
    for (int r = 0; r < 4; ++r) {
      float v = acc[dt][r] * invr[r];
      float ge = 0.5f * v * (1.0f + erff(v * 0.70710678118654752f));
      gbase[(size_t)(i0w + g4 + r) * IDV + cch] = (__bf16)ge;
    }
  }
}

// ---------------- out projection (prepped bf16 weights) ----------------
__global__ __launch_bounds__(256) void k_out(
    const __bf16* __restrict__ G, const __bf16* __restrict__ WB,
    const float* __restrict__ BB, float* __restrict__ out) {
  int b = blockIdx.z, oblk = blockIdx.x, iblk = blockIdx.y;
  int wave = threadIdx.x >> 6, lane = threadIdx.x & 63;
  int g = lane >> 4, l16 = lane & 15;
  int o0w = oblk * 64 + wave * 16;
  int ibase = iblk * 64;
  const __bf16* WoB = WB + 262144;
  const float* bo2 = BB + 1024;
  const __bf16* wrow = WoB + (size_t)(o0w + l16) * IDV;
  const __bf16* gb = G + (size_t)b * NCTX * IDV;
  f32x4 acc[4] = {};
#pragma unroll
  for (int kc = 0; kc < 16; ++kc) {
    int c = kc * 32 + g * 8;
    bf16x8 af = *reinterpret_cast<const bf16x8*>(wrow + c);
#pragma unroll
    for (int it = 0; it < 4; ++it) {
      bf16x8 bf = *reinterpret_cast<const bf16x8*>(
          gb + (size_t)(ibase + it * 16 + l16) * IDV + c);
      acc[it] = __builtin_amdgcn_mfma_f32_16x16x32_bf16(af, bf, acc[it], 0, 0, 0);
    }
  }
#pragma unroll
  for (int r = 0; r < 4; ++r) {
    int o = o0w + g * 4 + r;
    float bia = bo2[o];
#pragma unroll
    for (int it = 0; it < 4; ++it) {
      int i = ibase + it * 16 + l16;
      out[((size_t)b * DIM + o) * NCTX + i] = acc[it][r] + bia;
    }
  }
}

extern "C" void kernel_launch(void* const* d_in, const int* in_sizes, int n_in,
                              void* d_out, int out_size, void* d_ws, size_t ws_size,
                              hipStream_t stream) {
  const float* x  = (const float*)d_in[0];
  const float* Wq = (const float*)d_in[1];
  const float* Wk = (const float*)d_in[2];
  const float* Wv = (const float*)d_in[3];
  const float* Wo = (const float*)d_in[4];
  const float* bo = (const float*)d_in[5];
  const float* pe = (const float*)d_in[6];
  const float* qg = (const float*)d_in[7];
  const float* qb = (const float*)d_in[8];
  const float* qm = (const float*)d_in[9];
  const float* qv = (const float*)d_in[10];
  const float* kg = (const float*)d_in[11];
  const float* kb = (const float*)d_in[12];
  const float* km = (const float*)d_in[13];
  const float* kv = (const float*)d_in[14];
  const float* vg = (const float*)d_in[15];
  const float* vb = (const float*)d_in[16];
  const float* vm = (const float*)d_in[17];
  const float* vv = (const float*)d_in[18];
  const float* og = (const float*)d_in[19];
  const float* ob = (const float*)d_in[20];
  const float* om = (const float*)d_in[21];
  const float* ov = (const float*)d_in[22];

  char* ws = (char*)d_ws;
  __bf16* xT = (__bf16*)(ws);                       // 4 MB
  __bf16* Q  = (__bf16*)(ws + (4ull << 20));        // 4 MB
  __bf16* K  = (__bf16*)(ws + (8ull << 20));        // 4 MB
  __bf16* V  = (__bf16*)(ws + (12ull << 20));       // 8 MB
  __bf16* G  = (__bf16*)(ws + (20ull << 20));       // 8 MB
  __bf16* WB = (__bf16*)(ws + (28ull << 20));       // 768 KB bf16 weights
  float*  BB = (float*)(ws + (28ull << 20) + (768ull << 10));  // 5 KB biases
  float* out = (float*)d_out;

  k_prep<<<dim3(1541), 256, 0, stream>>>(Wq, Wk, Wv, Wo, bo, qg, qb, qm, qv,
                                         kg, kb, km, kv, vg, vb, vm, vv,
                                         og, ob, om, ov, WB, BB);
  k_transpose<<<dim3(16, 4, NB), 256, 0, stream>>>(x, xT);
  k_proj_qk<<<dim3(16, 8, NB), 256, 0, stream>>>(xT, WB, BB, Q, K);
  k_proj_v<<<dim3(8, 16, NB), 256, 0, stream>>>(xT, WB, BB, V);
  k_attn<<<dim3(16, 64), 256, 0, stream>>>(Q, K, V, pe, G);
  k_out<<<dim3(4, 16, NB), 256, 0, stream>>>(G, WB, BB, out);
}

// Round 5
// 99.489 us; speedup vs baseline: 1.7563x; 1.1076x over previous
//
#include <hip/hip_runtime.h>
#include <hip/hip_bf16.h>

#define HEADS 8
#define DK 32
#define DV 64
#define DIM 256
#define NCTX 1024
#define NB 8
#define IDK 256
#define IDV 512
#define SCALE 0.17677669529663687f
#define INV_SCALE 5.656854249492381f
#define BN_EPS 1e-5f
#define THR 8.0f

typedef __bf16 bf16x8 __attribute__((ext_vector_type(8)));
typedef __bf16 bf16x4 __attribute__((ext_vector_type(4)));
typedef float f32x4 __attribute__((ext_vector_type(4)));
typedef float f32x16 __attribute__((ext_vector_type(16)));

static __device__ __forceinline__ unsigned short bfbits(float v) {
  __bf16 b = (__bf16)v;
  return __builtin_bit_cast(unsigned short, b);
}

// ---------------- prep (weights+bias+bias-table) U transpose ----------------
// WB: WqB[65536] | WkB[65536] | WvB[131072] | WoB[131072] (bf16)
// BB: bq[256] | bk[256] | bv[512] | bo2[256] (f32)
// Tq4g[h][t] (uint2 = 4 bf16): elems rr=0..3 = pe_h[|t-rr-1023|]*INV_SCALE
__global__ __launch_bounds__(256) void k_prep_trans(
    const float* __restrict__ x,
    const float* __restrict__ Wq, const float* __restrict__ Wk,
    const float* __restrict__ Wv, const float* __restrict__ Wo,
    const float* __restrict__ bo, const float* __restrict__ pe,
    const float* __restrict__ qg, const float* __restrict__ qb,
    const float* __restrict__ qm, const float* __restrict__ qv,
    const float* __restrict__ kg, const float* __restrict__ kb,
    const float* __restrict__ km, const float* __restrict__ kv,
    const float* __restrict__ vg, const float* __restrict__ vb,
    const float* __restrict__ vm, const float* __restrict__ vv,
    const float* __restrict__ og, const float* __restrict__ ob,
    const float* __restrict__ om, const float* __restrict__ ov,
    __bf16* __restrict__ xT, __bf16* __restrict__ WB, float* __restrict__ BB,
    uint2* __restrict__ Tq4g) {
  int bid = blockIdx.x;
  if (bid < 1605) {
    int idx = bid * 256 + threadIdx.x;
    if (idx < 65536) {
      int o = idx >> 8;
      WB[idx] = (__bf16)(Wq[idx] * (qg[o] * rsqrtf(qv[o] + BN_EPS) * SCALE));
    } else if (idx < 131072) {
      int i = idx - 65536, o = i >> 8;
      WB[idx] = (__bf16)(Wk[i] * (kg[o] * rsqrtf(kv[o] + BN_EPS)));
    } else if (idx < 262144) {
      int i = idx - 131072, o = i >> 8;
      WB[idx] = (__bf16)(Wv[i] * (vg[o] * rsqrtf(vv[o] + BN_EPS)));
    } else if (idx < 393216) {
      int i = idx - 262144, o = i >> 9;
      WB[idx] = (__bf16)(Wo[i] * (og[o] * rsqrtf(ov[o] + BN_EPS)));
    } else if (idx < 394496) {
      int i = idx - 393216;
      if (i < 256) {
        float sc = qg[i] * rsqrtf(qv[i] + BN_EPS);
        BB[i] = (qb[i] - qm[i] * sc) * SCALE;
      } else if (i < 512) {
        int o = i - 256;
        float sc = kg[o] * rsqrtf(kv[o] + BN_EPS);
        BB[i] = kb[o] - km[o] * sc;
      } else if (i < 1024) {
        int o = i - 512;
        float sc = vg[o] * rsqrtf(vv[o] + BN_EPS);
        BB[i] = vb[o] - vm[o] * sc;
      } else {
        int o = i - 1024;
        float sc = og[o] * rsqrtf(ov[o] + BN_EPS);
        BB[i] = (bo[o] - om[o]) * sc + ob[o];
      }
    } else {
      int i = idx - 394496;          // 8 * 2048 entries
      int h = i >> 11, t = i & 2047;
      unsigned short us[4];
#pragma unroll
      for (int rr = 0; rr < 4; ++rr) {
        int d = t - rr - 1023; d = d < 0 ? -d : d; d = d > 1023 ? 1023 : d;
        us[rr] = bfbits(pe[(size_t)d * HEADS + h] * INV_SCALE);
      }
      uint2 e;
      e.x = (unsigned)us[0] | ((unsigned)us[1] << 16);
      e.y = (unsigned)us[2] | ((unsigned)us[3] << 16);
      Tq4g[((size_t)h << 11) + t] = e;
    }
  } else {
    // transpose x[b,c,n] f32 -> xT[b,n,c] bf16
    __shared__ float t[64][65];
    int tb = bid - 1605;
    int b = tb >> 6, c0 = ((tb >> 4) & 3) * 64, n0 = (tb & 15) * 64;
    int col = threadIdx.x & 63, rb = threadIdx.x >> 6;
    const float* xp = x + ((size_t)b * DIM + c0) * NCTX + n0;
#pragma unroll
    for (int r = 0; r < 16; ++r) {
      int row = rb + 4 * r;
      t[row][col] = xp[(size_t)row * NCTX + col];
    }
    __syncthreads();
    __bf16* op = xT + ((size_t)b * NCTX + n0) * DIM + c0;
#pragma unroll
    for (int r = 0; r < 16; ++r) {
      int i = rb + 4 * r;
      op[(size_t)i * DIM + col] = (__bf16)t[col][i];
    }
  }
}

// ---------------- fused QKV projection (prepped bf16 weights) ----------------
__global__ __launch_bounds__(256) void k_qkv(
    const __bf16* __restrict__ xT, const __bf16* __restrict__ WB,
    const float* __restrict__ BB, __bf16* __restrict__ Qws,
    __bf16* __restrict__ Kws, __bf16* __restrict__ Vws) {
  int b = blockIdx.z, sel = blockIdx.y, iblk = blockIdx.x;
  int wave = threadIdx.x >> 6, lane = threadIdx.x & 63;
  int g = lane >> 4, l16 = lane & 15;
  if (sel < 8) {  // Q (0-3) / K (4-7): A=xT (M=i), B=W (N=o)
    bool isQ = sel < 4;
    const __bf16* W = isQ ? WB : WB + 65536;
    const float* bias = isQ ? BB : BB + 256;
    int obase = (sel & 3) * 64;
    int i0w = iblk * 64 + wave * 16;
    const __bf16* xrow = xT + ((size_t)b * NCTX + i0w + l16) * DIM;
    f32x4 acc[4] = {};
#pragma unroll
    for (int kc = 0; kc < 8; ++kc) {
      int c = kc * 32 + g * 8;
      bf16x8 a = *reinterpret_cast<const bf16x8*>(xrow + c);
#pragma unroll
      for (int ot = 0; ot < 4; ++ot) {
        bf16x8 bf = *reinterpret_cast<const bf16x8*>(W + (size_t)(obase + ot * 16 + l16) * DIM + c);
        acc[ot] = __builtin_amdgcn_mfma_f32_16x16x32_bf16(a, bf, acc[ot], 0, 0, 0);
      }
    }
    __bf16* OWS = isQ ? Qws : Kws;
#pragma unroll
    for (int ot = 0; ot < 4; ++ot) {
      int o = obase + ot * 16 + l16;
      float bia = bias[o];
      int h = o >> 5, d = o & 31;
#pragma unroll
      for (int r = 0; r < 4; ++r) {
        int i = i0w + g * 4 + r;
        OWS[(((size_t)b * HEADS + h) * NCTX + i) * DK + d] = (__bf16)(acc[ot][r] + bia);
      }
    }
  } else {  // V: A=Wv (M=o), B=xT (N=i), output [o][n]
    int oblk = sel - 8;
    int o0w = oblk * 64 + wave * 16;
    int ibase = iblk * 64;
    const __bf16* WvB = WB + 131072;
    const float* bv = BB + 512;
    const __bf16* wrow = WvB + (size_t)(o0w + l16) * DIM;
    f32x4 acc[4] = {};
#pragma unroll
    for (int kc = 0; kc < 8; ++kc) {
      int c = kc * 32 + g * 8;
      bf16x8 af = *reinterpret_cast<const bf16x8*>(wrow + c);
#pragma unroll
      for (int it = 0; it < 4; ++it) {
        bf16x8 bf = *reinterpret_cast<const bf16x8*>(
            xT + ((size_t)b * NCTX + ibase + it * 16 + l16) * DIM + c);
        acc[it] = __builtin_amdgcn_mfma_f32_16x16x32_bf16(af, bf, acc[it], 0, 0, 0);
      }
    }
#pragma unroll
    for (int r = 0; r < 4; ++r) {
      int o = o0w + g * 4 + r;
      float bia = bv[o];
#pragma unroll
      for (int it = 0; it < 4; ++it) {
        int i = ibase + it * 16 + l16;
        Vws[((size_t)b * IDV + o) * NCTX + i] = (__bf16)(acc[it][r] + bia);
      }
    }
  }
}

// ---------------- attention: 32x32 MFMA, in-register P, bf16x4 bias table ------
// Block = 128 q-rows (4 waves x 32), j-tile 64. Lane owns q-row (lane&31).
// K LDS [64][40] (conflict-balanced), V LDS [64][64] with slot^(row&7) swizzle.
__global__ __launch_bounds__(256, 2) void k_attn(
    const __bf16* __restrict__ Qws, const __bf16* __restrict__ Kws,
    const __bf16* __restrict__ Vws, const uint2* __restrict__ Tq4g,
    __bf16* __restrict__ G) {
  int flat = blockIdx.x;                       // 512
  int swz = (flat & 7) * 64 + (flat >> 3);     // XCD-aware: 64 consecutive ids/XCD
  int iblk = swz & 7, bh = swz >> 3;
  int b = bh >> 3, h = bh & 7;
  int tid = threadIdx.x, wave = tid >> 6, lane = tid & 63;
  int l31 = lane & 31, hi = lane >> 5;

  __shared__ __align__(16) __bf16 Klds[64][40];
  __shared__ __align__(16) __bf16 Vlds[64 * 64];
  __shared__ __align__(16) uint2 TqL[1152];

  int i0b = iblk * 128;
  // stage bias table slice [i0b .. i0b+1151]
  {
    const uint4* tg4 = reinterpret_cast<const uint4*>(Tq4g + ((size_t)h << 11) + i0b);
    uint4* tl4 = reinterpret_cast<uint4*>(TqL);
    for (int c = tid; c < 576; c += 256) tl4[c] = tg4[c];
  }

  int i0w = i0b + wave * 32;
  int irow = i0w + l31;
  const __bf16* qbase = Qws + (size_t)bh * NCTX * DK;
  const __bf16* kbase = Kws + (size_t)bh * NCTX * DK;
  const __bf16* vbase = Vws + ((size_t)b * IDV + h * DV) * NCTX;
  bf16x8 qf0 = *reinterpret_cast<const bf16x8*>(qbase + (size_t)irow * DK + 8 * hi);
  bf16x8 qf1 = *reinterpret_cast<const bf16x8*>(qbase + (size_t)irow * DK + 16 + 8 * hi);

  // staging map: thread -> K row r_ slot sk; V row r_ slots sk, sk+4 (swizzled)
  int r_ = tid >> 2, sk = tid & 3;
  const __bf16* kgp = kbase + (size_t)r_ * DK + 8 * sk;
  const __bf16* vgp = vbase + (size_t)r_ * NCTX + 8 * sk;
  __bf16* kw = &Klds[r_][8 * sk];
  __bf16* vw0 = Vlds + r_ * 64 + 8 * (sk ^ (r_ & 7));
  __bf16* vw1 = Vlds + r_ * 64 + 8 * ((sk + 4) ^ (r_ & 7));

  bf16x8 rk = *reinterpret_cast<const bf16x8*>(kgp);
  bf16x8 rv0 = *reinterpret_cast<const bf16x8*>(vgp);
  bf16x8 rv1 = *reinterpret_cast<const bf16x8*>(vgp + 32);

  f32x16 acc0 = {}, acc1 = {};
  float m = -1e30f, s = 0.0f;
  int kxb = wave * 32 + l31 + 1023 - 4 * hi;   // bias entry base (block-local)
  const bf16x4* Tqp = reinterpret_cast<const bf16x4*>(TqL);

  for (int it = 0; it < 16; ++it) {
    int j0 = it * 64;
    __syncthreads();  // A: previous compute done with LDS (+ TqL staged, iter 0)
    *reinterpret_cast<bf16x8*>(kw) = rk;
    *reinterpret_cast<bf16x8*>(vw0) = rv0;
    *reinterpret_cast<bf16x8*>(vw1) = rv1;
    __syncthreads();  // B: tile visible
    int jn = (j0 + 64) & (NCTX - 1);
    rk = *reinterpret_cast<const bf16x8*>(kgp + (size_t)jn * DK);
    rv0 = *reinterpret_cast<const bf16x8*>(vgp + jn);
    rv1 = *reinterpret_cast<const bf16x8*>(vgp + jn + 32);

    // S^T: A=K rows (m=j), B=Q (n=i); chained over dk
    float sv[32];
#pragma unroll
    for (int jg = 0; jg < 2; ++jg) {
      bf16x8 kf0 = *reinterpret_cast<const bf16x8*>(&Klds[32 * jg + l31][8 * hi]);
      bf16x8 kf1 = *reinterpret_cast<const bf16x8*>(&Klds[32 * jg + l31][16 + 8 * hi]);
      f32x16 S = {};
      S = __builtin_amdgcn_mfma_f32_32x32x16_bf16(kf0, qf0, S, 0, 0, 0);
      S = __builtin_amdgcn_mfma_f32_32x32x16_bf16(kf1, qf1, S, 0, 0, 0);
      int kb_ = kxb - j0 - 32 * jg;
#pragma unroll
      for (int q = 0; q < 4; ++q) {
        bf16x4 q4 = Tqp[kb_ - 8 * q];
#pragma unroll
        for (int rr = 0; rr < 4; ++rr)
          sv[jg * 16 + q * 4 + rr] = S[q * 4 + rr] + (float)q4[rr];
      }
    }
    float pmax = sv[0];
#pragma unroll
    for (int k = 1; k < 32; ++k) pmax = fmaxf(pmax, sv[k]);
    if (__any(pmax > m + THR)) {  // rare after first tile
      float mx = fmaxf(pmax, __shfl_xor(pmax, 32));
      float mnew = fmaxf(m, mx);
      float corr = __expf(m - mnew);
      s *= corr; m = mnew;
#pragma unroll
      for (int r = 0; r < 16; ++r) {
        float cv = __shfl(corr, (r & 3) + 8 * (r >> 2) + 4 * hi);
        acc0[r] *= cv; acc1[r] *= cv;
      }
    }
#pragma unroll
    for (int k = 0; k < 32; ++k) sv[k] = __expf(sv[k] - m);
    float ps = 0.0f;
#pragma unroll
    for (int k = 0; k < 32; ++k) ps += sv[k];
    s += ps;
    // P -> A-frags fully in-register: cvt_pk pairs + permlane32 swap
#pragma unroll
    for (int jg = 0; jg < 2; ++jg) {
#pragma unroll
      for (int u = 0; u < 2; ++u) {
        int base = jg * 16 + 8 * u;
        unsigned we0, we1, wo0, wo1;
        asm("v_cvt_pk_bf16_f32 %0, %1, %2" : "=v"(we0) : "v"(sv[base + 0]), "v"(sv[base + 1]));
        asm("v_cvt_pk_bf16_f32 %0, %1, %2" : "=v"(we1) : "v"(sv[base + 2]), "v"(sv[base + 3]));
        asm("v_cvt_pk_bf16_f32 %0, %1, %2" : "=v"(wo0) : "v"(sv[base + 4]), "v"(sv[base + 5]));
        asm("v_cvt_pk_bf16_f32 %0, %1, %2" : "=v"(wo1) : "v"(sv[base + 6]), "v"(sv[base + 7]));
        asm volatile("v_permlane32_swap_b32 %0, %1" : "+v"(we0), "+v"(wo0));
        asm volatile("v_permlane32_swap_b32 %0, %1" : "+v"(we1), "+v"(wo1));
        uint4 pw = {we0, we1, wo0, wo1};
        bf16x8 pfrag = *reinterpret_cast<bf16x8*>(&pw);
        int c = jg * 2 + u;
        int sl = 2 * c + hi;
        bf16x8 vf0 = *reinterpret_cast<const bf16x8*>(Vlds + l31 * 64 + 8 * (sl ^ (l31 & 7)));
        bf16x8 vf1 = *reinterpret_cast<const bf16x8*>(Vlds + (32 + l31) * 64 + 8 * (sl ^ (l31 & 7)));
        acc0 = __builtin_amdgcn_mfma_f32_32x32x16_bf16(pfrag, vf0, acc0, 0, 0, 0);
        acc1 = __builtin_amdgcn_mfma_f32_32x32x16_bf16(pfrag, vf1, acc1, 0, 0, 0);
      }
    }
  }
  // epilogue: row-sum across hi halves, /s, exact gelu, store
  float srow = s + __shfl_xor(s, 32);
  float inv = 1.0f / srow;
  __bf16* gbase = G + (size_t)b * NCTX * IDV + h * DV + l31;
#pragma unroll
  for (int r = 0; r < 16; ++r) {
    int il = (r & 3) + 8 * (r >> 2) + 4 * hi;
    float iv = __shfl(inv, il);
    float v0 = acc0[r] * iv, v1 = acc1[r] * iv;
    float g0 = 0.5f * v0 * (1.0f + erff(v0 * 0.70710678118654752f));
    float g1 = 0.5f * v1 * (1.0f + erff(v1 * 0.70710678118654752f));
    gbase[(size_t)(i0w + il) * IDV] = (__bf16)g0;
    gbase[(size_t)(i0w + il) * IDV + 32] = (__bf16)g1;
  }
}

// ---------------- out projection (prepped bf16 weights) ----------------
__global__ __launch_bounds__(256) void k_out(
    const __bf16* __restrict__ G, const __bf16* __restrict__ WB,
    const float* __restrict__ BB, float* __restrict__ out) {
  int b = blockIdx.z, oblk = blockIdx.x, iblk = blockIdx.y;
  int wave = threadIdx.x >> 6, lane = threadIdx.x & 63;
  int g = lane >> 4, l16 = lane & 15;
  int o0w = oblk * 64 + wave * 16;
  int ibase = iblk * 64;
  const __bf16* WoB = WB + 262144;
  const float* bo2 = BB + 1024;
  const __bf16* wrow = WoB + (size_t)(o0w + l16) * IDV;
  const __bf16* gb = G + (size_t)b * NCTX * IDV;
  f32x4 acc[4] = {};
#pragma unroll
  for (int kc = 0; kc < 16; ++kc) {
    int c = kc * 32 + g * 8;
    bf16x8 af = *reinterpret_cast<const bf16x8*>(wrow + c);
#pragma unroll
    for (int it = 0; it < 4; ++it) {
      bf16x8 bf = *reinterpret_cast<const bf16x8*>(
          gb + (size_t)(ibase + it * 16 + l16) * IDV + c);
      acc[it] = __builtin_amdgcn_mfma_f32_16x16x32_bf16(af, bf, acc[it], 0, 0, 0);
    }
  }
#pragma unroll
  for (int r = 0; r < 4; ++r) {
    int o = o0w + g * 4 + r;
    float bia = bo2[o];
#pragma unroll
    for (int it = 0; it < 4; ++it) {
      int i = ibase + it * 16 + l16;
      out[((size_t)b * DIM + o) * NCTX + i] = acc[it][r] + bia;
    }
  }
}

extern "C" void kernel_launch(void* const* d_in, const int* in_sizes, int n_in,
                              void* d_out, int out_size, void* d_ws, size_t ws_size,
                              hipStream_t stream) {
  const float* x  = (const float*)d_in[0];
  const float* Wq = (const float*)d_in[1];
  const float* Wk = (const float*)d_in[2];
  const float* Wv = (const float*)d_in[3];
  const float* Wo = (const float*)d_in[4];
  const float* bo = (const float*)d_in[5];
  const float* pe = (const float*)d_in[6];
  const float* qg = (const float*)d_in[7];
  const float* qb = (const float*)d_in[8];
  const float* qm = (const float*)d_in[9];
  const float* qv = (const float*)d_in[10];
  const float* kg = (const float*)d_in[11];
  const float* kb = (const float*)d_in[12];
  const float* km = (const float*)d_in[13];
  const float* kv = (const float*)d_in[14];
  const float* vg = (const float*)d_in[15];
  const float* vb = (const float*)d_in[16];
  const float* vm = (const float*)d_in[17];
  const float* vv = (const float*)d_in[18];
  const float* og = (const float*)d_in[19];
  const float* ob = (const float*)d_in[20];
  const float* om = (const float*)d_in[21];
  const float* ov = (const float*)d_in[22];

  char* ws = (char*)d_ws;
  __bf16* xT = (__bf16*)(ws);                       // 4 MB
  __bf16* Q  = (__bf16*)(ws + (4ull << 20));        // 4 MB
  __bf16* K  = (__bf16*)(ws + (8ull << 20));        // 4 MB
  __bf16* V  = (__bf16*)(ws + (12ull << 20));       // 8 MB
  __bf16* G  = (__bf16*)(ws + (20ull << 20));       // 8 MB
  __bf16* WB = (__bf16*)(ws + (28ull << 20));       // 768 KB bf16 weights
  float*  BB = (float*)(ws + (28ull << 20) + (768ull << 10));  // 5 KB biases
  uint2*  Tq = (uint2*)(ws + (29ull << 20));        // 128 KB bias table
  float* out = (float*)d_out;

  k_prep_trans<<<dim3(2117), 256, 0, stream>>>(
      x, Wq, Wk, Wv, Wo, bo, pe, qg, qb, qm, qv, kg, kb, km, kv,
      vg, vb, vm, vv, og, ob, om, ov, xT, WB, BB, Tq);
  k_qkv<<<dim3(16, 16, NB), 256, 0, stream>>>(xT, WB, BB, Q, K, V);
  k_attn<<<dim3(512), 256, 0, stream>>>(Q, K, V, Tq, G);
  k_out<<<dim3(4, 16, NB), 256, 0, stream>>>(G, WB, BB, out);
}

// Round 6
// 63.566 us; speedup vs baseline: 2.7488x; 1.5651x over previous
//
#include <hip/hip_runtime.h>
#include <hip/hip_bf16.h>

#define HEADS 8
#define DK 32
#define DV 64
#define DIM 256
#define NCTX 1024
#define NB 8
#define IDK 256
#define IDV 512
#define SCALE 0.17677669529663687f
#define INV_SCALE 5.656854249492381f
#define BN_EPS 1e-5f
#define THR 8.0f

typedef __bf16 bf16x8 __attribute__((ext_vector_type(8)));
typedef __bf16 bf16x4 __attribute__((ext_vector_type(4)));
typedef float f32x4 __attribute__((ext_vector_type(4)));
typedef float f32x16 __attribute__((ext_vector_type(16)));

static __device__ __forceinline__ unsigned short bfbits(float v) {
  __bf16 b = (__bf16)v;
  return __builtin_bit_cast(unsigned short, b);
}

// ---------------- prep (weights+bias+bias-table) U transpose ----------------
// WB: stacked rows [1024][256]: WqB(0-255) | WkB(256-511) | WvB(512-1023), then WoB[256][512]
// BB: bq[256] | bk[256] | bv[512] | bo2[256] (f32)
// Tq4g[h][t] (uint2 = 4 bf16): elems rr=0..3 = pe_h[|t-rr-1023|]*INV_SCALE
__global__ __launch_bounds__(256) void k_prep_trans(
    const float* __restrict__ x,
    const float* __restrict__ Wq, const float* __restrict__ Wk,
    const float* __restrict__ Wv, const float* __restrict__ Wo,
    const float* __restrict__ bo, const float* __restrict__ pe,
    const float* __restrict__ qg, const float* __restrict__ qb,
    const float* __restrict__ qm, const float* __restrict__ qv,
    const float* __restrict__ kg, const float* __restrict__ kb,
    const float* __restrict__ km, const float* __restrict__ kv,
    const float* __restrict__ vg, const float* __restrict__ vb,
    const float* __restrict__ vm, const float* __restrict__ vv,
    const float* __restrict__ og, const float* __restrict__ ob,
    const float* __restrict__ om, const float* __restrict__ ov,
    __bf16* __restrict__ xT, __bf16* __restrict__ WB, float* __restrict__ BB,
    uint2* __restrict__ Tq4g) {
  int bid = blockIdx.x;
  if (bid < 1605) {
    int idx = bid * 256 + threadIdx.x;
    if (idx < 65536) {
      int o = idx >> 8;
      WB[idx] = (__bf16)(Wq[idx] * (qg[o] * rsqrtf(qv[o] + BN_EPS) * SCALE));
    } else if (idx < 131072) {
      int i = idx - 65536, o = i >> 8;
      WB[idx] = (__bf16)(Wk[i] * (kg[o] * rsqrtf(kv[o] + BN_EPS)));
    } else if (idx < 262144) {
      int i = idx - 131072, o = i >> 8;
      WB[idx] = (__bf16)(Wv[i] * (vg[o] * rsqrtf(vv[o] + BN_EPS)));
    } else if (idx < 393216) {
      int i = idx - 262144, o = i >> 9;
      WB[idx] = (__bf16)(Wo[i] * (og[o] * rsqrtf(ov[o] + BN_EPS)));
    } else if (idx < 394496) {
      int i = idx - 393216;
      if (i < 256) {
        float sc = qg[i] * rsqrtf(qv[i] + BN_EPS);
        BB[i] = (qb[i] - qm[i] * sc) * SCALE;
      } else if (i < 512) {
        int o = i - 256;
        float sc = kg[o] * rsqrtf(kv[o] + BN_EPS);
        BB[i] = kb[o] - km[o] * sc;
      } else if (i < 1024) {
        int o = i - 512;
        float sc = vg[o] * rsqrtf(vv[o] + BN_EPS);
        BB[i] = vb[o] - vm[o] * sc;
      } else {
        int o = i - 1024;
        float sc = og[o] * rsqrtf(ov[o] + BN_EPS);
        BB[i] = (bo[o] - om[o]) * sc + ob[o];
      }
    } else {
      int i = idx - 394496;          // 8 * 2048 entries
      int h = i >> 11, t = i & 2047;
      unsigned short us[4];
#pragma unroll
      for (int rr = 0; rr < 4; ++rr) {
        int d = t - rr - 1023; d = d < 0 ? -d : d; d = d > 1023 ? 1023 : d;
        us[rr] = bfbits(pe[(size_t)d * HEADS + h] * INV_SCALE);
      }
      uint2 e;
      e.x = (unsigned)us[0] | ((unsigned)us[1] << 16);
      e.y = (unsigned)us[2] | ((unsigned)us[3] << 16);
      Tq4g[((size_t)h << 11) + t] = e;
    }
  } else {
    // transpose x[b,c,n] f32 -> xT[b,n,c] bf16
    __shared__ float t[64][65];
    int tb = bid - 1605;
    int b = tb >> 6, c0 = ((tb >> 4) & 3) * 64, n0 = (tb & 15) * 64;
    int col = threadIdx.x & 63, rb = threadIdx.x >> 6;
    const float* xp = x + ((size_t)b * DIM + c0) * NCTX + n0;
#pragma unroll
    for (int r = 0; r < 16; ++r) {
      int row = rb + 4 * r;
      t[row][col] = xp[(size_t)row * NCTX + col];
    }
    __syncthreads();
    __bf16* op = xT + ((size_t)b * NCTX + n0) * DIM + c0;
#pragma unroll
    for (int r = 0; r < 16; ++r) {
      int i = rb + 4 * r;
      op[(size_t)i * DIM + col] = (__bf16)t[col][i];
    }
  }
}

// ---------------- tiled GEMM: 128x128 block, XOR-swizzled LDS, packed stores ----
// mode 0: Q (swapped: m=o, n=i)   mode 1: K (swapped)
// mode 2: V (natural: m=i, n=o, out [vo][n])  mode 3: out-proj (natural, f32 out)
__global__ __launch_bounds__(256, 2) void k_gemm(
    const __bf16* __restrict__ Xsrc, const __bf16* __restrict__ Wsrc,
    const float* __restrict__ Bias, __bf16* __restrict__ Qws,
    __bf16* __restrict__ Kws, __bf16* __restrict__ Vws,
    float* __restrict__ Oout, int lda, int ksteps, int mode_base) {
  int bx = blockIdx.x, by = blockIdx.y;
  int mode = (mode_base == 3) ? 3 : (by < 2 ? 0 : (by < 4 ? 1 : 2));
  int tid = threadIdx.x, wave = tid >> 6, lane = tid & 63;
  int wm = wave >> 1, wn = wave & 1;
  int l16 = lane & 15, g = (lane >> 4) & 3, g4 = g * 4;
  int R0 = bx * 128;

  __shared__ __align__(16) char XTl[16384];   // [128 rows][64 bf16], swizzled granules
  __shared__ __align__(16) char WTl[16384];

  // staging map: 2 threads per row, 4x16B granules each
  int sr = tid >> 1, sh = tid & 1;
  const __bf16* xg = Xsrc + (size_t)(R0 + sr) * lda + sh * 32;
  const __bf16* wg = Wsrc + (size_t)(by * 128 + sr) * lda + sh * 32;
  int wbase = sr * 128;
  int gsw[4];
#pragma unroll
  for (int q = 0; q < 4; ++q) gsw[q] = ((sh * 4 + q) ^ (sr & 7)) * 16;

  bf16x8 sx[4], sw[4];
#pragma unroll
  for (int q = 0; q < 4; ++q) {
    sx[q] = *reinterpret_cast<const bf16x8*>(xg + q * 8);
    sw[q] = *reinterpret_cast<const bf16x8*>(wg + q * 8);
  }

  f32x4 acc[4][4] = {};
  const char* Abase = (mode <= 1) ? WTl : XTl;
  const char* Bbase = (mode <= 1) ? XTl : WTl;

  for (int st = 0; st < ksteps; ++st) {
    __syncthreads();   // A: all reads of previous tile done
#pragma unroll
    for (int q = 0; q < 4; ++q) {
      *reinterpret_cast<bf16x8*>(XTl + wbase + gsw[q]) = sx[q];
      *reinterpret_cast<bf16x8*>(WTl + wbase + gsw[q]) = sw[q];
    }
    __syncthreads();   // B: tile visible
    if (st + 1 < ksteps) {   // T14: issue next-step loads, fly across compute
      const __bf16* xn = xg + (st + 1) * 64;
      const __bf16* wn_ = wg + (st + 1) * 64;
#pragma unroll
      for (int q = 0; q < 4; ++q) {
        sx[q] = *reinterpret_cast<const bf16x8*>(xn + q * 8);
        sw[q] = *reinterpret_cast<const bf16x8*>(wn_ + q * 8);
      }
    }
#pragma unroll
    for (int kc = 0; kc < 2; ++kc) {
      bf16x8 af[4], bf[4];
#pragma unroll
      for (int t = 0; t < 4; ++t) {
        int ra = wm * 64 + t * 16 + l16;
        af[t] = *reinterpret_cast<const bf16x8*>(
            Abase + ra * 128 + (((kc * 4 + g) ^ (ra & 7)) * 16));
        int rb = wn * 64 + t * 16 + l16;
        bf[t] = *reinterpret_cast<const bf16x8*>(
            Bbase + rb * 128 + (((kc * 4 + g) ^ (rb & 7)) * 16));
      }
#pragma unroll
      for (int mt = 0; mt < 4; ++mt)
#pragma unroll
        for (int nt = 0; nt < 4; ++nt)
          acc[mt][nt] = __builtin_amdgcn_mfma_f32_16x16x32_bf16(
              af[mt], bf[nt], acc[mt][nt], 0, 0, 0);
    }
  }

  if (mode <= 1) {  // Q/K: acc[m=o][n=i]; pack 4 consecutive d per lane -> b64
    __bf16* OWS = (mode == 0) ? Qws : Kws;
    const float* bb = Bias + (mode == 0 ? 0 : 256);
    int oq0 = by * 128 - (mode == 1 ? 256 : 0) + wm * 64;
#pragma unroll
    for (int mt = 0; mt < 4; ++mt) {
      int oq = oq0 + mt * 16 + g4;
      float4 b4 = *reinterpret_cast<const float4*>(&bb[oq]);
      int h = oq >> 5, d0 = oq & 31;
#pragma unroll
      for (int nt = 0; nt < 4; ++nt) {
        int i = R0 + wn * 64 + nt * 16 + l16;
        int b = i >> 10, n = i & 1023;
        bf16x4 pk;
        pk[0] = (__bf16)(acc[mt][nt][0] + b4.x);
        pk[1] = (__bf16)(acc[mt][nt][1] + b4.y);
        pk[2] = (__bf16)(acc[mt][nt][2] + b4.z);
        pk[3] = (__bf16)(acc[mt][nt][3] + b4.w);
        *reinterpret_cast<bf16x4*>(
            &OWS[(((size_t)b * HEADS + h) * NCTX + n) * DK + d0]) = pk;
      }
    }
  } else if (mode == 2) {  // V: acc[m=i][n=vo]; pack 4 consecutive n -> b64
#pragma unroll
    for (int nt = 0; nt < 4; ++nt) {
      int vo = (by - 4) * 128 + wn * 64 + nt * 16 + l16;
      float bia = Bias[512 + vo];
#pragma unroll
      for (int mt = 0; mt < 4; ++mt) {
        int i0 = R0 + wm * 64 + mt * 16 + g4;
        int b = i0 >> 10, n = i0 & 1023;
        bf16x4 pk;
#pragma unroll
        for (int rr = 0; rr < 4; ++rr) pk[rr] = (__bf16)(acc[mt][nt][rr] + bia);
        *reinterpret_cast<bf16x4*>(&Vws[((size_t)b * IDV + vo) * NCTX + n]) = pk;
      }
    }
  } else {  // out-proj: acc[m=i][n=o]; pack float4 of consecutive n
#pragma unroll
    for (int nt = 0; nt < 4; ++nt) {
      int o = by * 128 + wn * 64 + nt * 16 + l16;
      float bia = Bias[o];
#pragma unroll
      for (int mt = 0; mt < 4; ++mt) {
        int i0 = R0 + wm * 64 + mt * 16 + g4;
        int b = i0 >> 10, n = i0 & 1023;
        float4 st;
        st.x = acc[mt][nt][0] + bia;
        st.y = acc[mt][nt][1] + bia;
        st.z = acc[mt][nt][2] + bia;
        st.w = acc[mt][nt][3] + bia;
        *reinterpret_cast<float4*>(&Oout[((size_t)b * DIM + o) * NCTX + n]) = st;
      }
    }
  }
}

// ---------------- attention: 32x32 MFMA, in-register P, bf16x4 bias table ------
__global__ __launch_bounds__(256, 2) void k_attn(
    const __bf16* __restrict__ Qws, const __bf16* __restrict__ Kws,
    const __bf16* __restrict__ Vws, const uint2* __restrict__ Tq4g,
    __bf16* __restrict__ G) {
  int flat = blockIdx.x;                       // 512
  int swz = (flat & 7) * 64 + (flat >> 3);     // XCD-aware: 64 consecutive ids/XCD
  int iblk = swz & 7, bh = swz >> 3;
  int b = bh >> 3, h = bh & 7;
  int tid = threadIdx.x, wave = tid >> 6, lane = tid & 63;
  int l31 = lane & 31, hi = lane >> 5;

  __shared__ __align__(16) __bf16 Klds[64][40];
  __shared__ __align__(16) __bf16 Vlds[64 * 64];
  __shared__ __align__(16) uint2 TqL[1152];

  int i0b = iblk * 128;
  {
    const uint4* tg4 = reinterpret_cast<const uint4*>(Tq4g + ((size_t)h << 11) + i0b);
    uint4* tl4 = reinterpret_cast<uint4*>(TqL);
    for (int c = tid; c < 576; c += 256) tl4[c] = tg4[c];
  }

  int i0w = i0b + wave * 32;
  int irow = i0w + l31;
  const __bf16* qbase = Qws + (size_t)bh * NCTX * DK;
  const __bf16* kbase = Kws + (size_t)bh * NCTX * DK;
  const __bf16* vbase = Vws + ((size_t)b * IDV + h * DV) * NCTX;
  bf16x8 qf0 = *reinterpret_cast<const bf16x8*>(qbase + (size_t)irow * DK + 8 * hi);
  bf16x8 qf1 = *reinterpret_cast<const bf16x8*>(qbase + (size_t)irow * DK + 16 + 8 * hi);

  int r_ = tid >> 2, sk = tid & 3;
  const __bf16* kgp = kbase + (size_t)r_ * DK + 8 * sk;
  const __bf16* vgp = vbase + (size_t)r_ * NCTX + 8 * sk;
  __bf16* kw = &Klds[r_][8 * sk];
  __bf16* vw0 = Vlds + r_ * 64 + 8 * (sk ^ (r_ & 7));
  __bf16* vw1 = Vlds + r_ * 64 + 8 * ((sk + 4) ^ (r_ & 7));

  bf16x8 rk = *reinterpret_cast<const bf16x8*>(kgp);
  bf16x8 rv0 = *reinterpret_cast<const bf16x8*>(vgp);
  bf16x8 rv1 = *reinterpret_cast<const bf16x8*>(vgp + 32);

  f32x16 acc0 = {}, acc1 = {};
  float m = -1e30f, s = 0.0f;
  int kxb = wave * 32 + l31 + 1023 - 4 * hi;
  const bf16x4* Tqp = reinterpret_cast<const bf16x4*>(TqL);

  for (int it = 0; it < 16; ++it) {
    int j0 = it * 64;
    __syncthreads();
    *reinterpret_cast<bf16x8*>(kw) = rk;
    *reinterpret_cast<bf16x8*>(vw0) = rv0;
    *reinterpret_cast<bf16x8*>(vw1) = rv1;
    __syncthreads();
    int jn = (j0 + 64) & (NCTX - 1);
    rk = *reinterpret_cast<const bf16x8*>(kgp + (size_t)jn * DK);
    rv0 = *reinterpret_cast<const bf16x8*>(vgp + jn);
    rv1 = *reinterpret_cast<const bf16x8*>(vgp + jn + 32);

    float sv[32];
#pragma unroll
    for (int jg = 0; jg < 2; ++jg) {
      bf16x8 kf0 = *reinterpret_cast<const bf16x8*>(&Klds[32 * jg + l31][8 * hi]);
      bf16x8 kf1 = *reinterpret_cast<const bf16x8*>(&Klds[32 * jg + l31][16 + 8 * hi]);
      f32x16 S = {};
      S = __builtin_amdgcn_mfma_f32_32x32x16_bf16(kf0, qf0, S, 0, 0, 0);
      S = __builtin_amdgcn_mfma_f32_32x32x16_bf16(kf1, qf1, S, 0, 0, 0);
      int kb_ = kxb - j0 - 32 * jg;
#pragma unroll
      for (int q = 0; q < 4; ++q) {
        bf16x4 q4 = Tqp[kb_ - 8 * q];
#pragma unroll
        for (int rr = 0; rr < 4; ++rr)
          sv[jg * 16 + q * 4 + rr] = S[q * 4 + rr] + (float)q4[rr];
      }
    }
    float pmax = sv[0];
#pragma unroll
    for (int k = 1; k < 32; ++k) pmax = fmaxf(pmax, sv[k]);
    if (__any(pmax > m + THR)) {
      float mx = fmaxf(pmax, __shfl_xor(pmax, 32));
      float mnew = fmaxf(m, mx);
      float corr = __expf(m - mnew);
      s *= corr; m = mnew;
#pragma unroll
      for (int r = 0; r < 16; ++r) {
        float cv = __shfl(corr, (r & 3) + 8 * (r >> 2) + 4 * hi);
        acc0[r] *= cv; acc1[r] *= cv;
      }
    }
#pragma unroll
    for (int k = 0; k < 32; ++k) sv[k] = __expf(sv[k] - m);
    float ps = 0.0f;
#pragma unroll
    for (int k = 0; k < 32; ++k) ps += sv[k];
    s += ps;
#pragma unroll
    for (int jg = 0; jg < 2; ++jg) {
#pragma unroll
      for (int u = 0; u < 2; ++u) {
        int base = jg * 16 + 8 * u;
        unsigned we0, we1, wo0, wo1;
        asm("v_cvt_pk_bf16_f32 %0, %1, %2" : "=v"(we0) : "v"(sv[base + 0]), "v"(sv[base + 1]));
        asm("v_cvt_pk_bf16_f32 %0, %1, %2" : "=v"(we1) : "v"(sv[base + 2]), "v"(sv[base + 3]));
        asm("v_cvt_pk_bf16_f32 %0, %1, %2" : "=v"(wo0) : "v"(sv[base + 4]), "v"(sv[base + 5]));
        asm("v_cvt_pk_bf16_f32 %0, %1, %2" : "=v"(wo1) : "v"(sv[base + 6]), "v"(sv[base + 7]));
        asm volatile("v_permlane32_swap_b32 %0, %1" : "+v"(we0), "+v"(wo0));
        asm volatile("v_permlane32_swap_b32 %0, %1" : "+v"(we1), "+v"(wo1));
        uint4 pw = {we0, we1, wo0, wo1};
        bf16x8 pfrag = *reinterpret_cast<bf16x8*>(&pw);
        int c = jg * 2 + u;
        int sl = 2 * c + hi;
        bf16x8 vf0 = *reinterpret_cast<const bf16x8*>(Vlds + l31 * 64 + 8 * (sl ^ (l31 & 7)));
        bf16x8 vf1 = *reinterpret_cast<const bf16x8*>(Vlds + (32 + l31) * 64 + 8 * (sl ^ (l31 & 7)));
        acc0 = __builtin_amdgcn_mfma_f32_32x32x16_bf16(pfrag, vf0, acc0, 0, 0, 0);
        acc1 = __builtin_amdgcn_mfma_f32_32x32x16_bf16(pfrag, vf1, acc1, 0, 0, 0);
      }
    }
  }
  float srow = s + __shfl_xor(s, 32);
  float inv = 1.0f / srow;
  __bf16* gbase = G + (size_t)b * NCTX * IDV + h * DV + l31;
#pragma unroll
  for (int r = 0; r < 16; ++r) {
    int il = (r & 3) + 8 * (r >> 2) + 4 * hi;
    float iv = __shfl(inv, il);
    float v0 = acc0[r] * iv, v1 = acc1[r] * iv;
    float g0 = 0.5f * v0 * (1.0f + erff(v0 * 0.70710678118654752f));
    float g1 = 0.5f * v1 * (1.0f + erff(v1 * 0.70710678118654752f));
    gbase[(size_t)(i0w + il) * IDV] = (__bf16)g0;
    gbase[(size_t)(i0w + il) * IDV + 32] = (__bf16)g1;
  }
}

extern "C" void kernel_launch(void* const* d_in, const int* in_sizes, int n_in,
                              void* d_out, int out_size, void* d_ws, size_t ws_size,
                              hipStream_t stream) {
  const float* x  = (const float*)d_in[0];
  const float* Wq = (const float*)d_in[1];
  const float* Wk = (const float*)d_in[2];
  const float* Wv = (const float*)d_in[3];
  const float* Wo = (const float*)d_in[4];
  const float* bo = (const float*)d_in[5];
  const float* pe = (const float*)d_in[6];
  const float* qg = (const float*)d_in[7];
  const float* qb = (const float*)d_in[8];
  const float* qm = (const float*)d_in[9];
  const float* qv = (const float*)d_in[10];
  const float* kg = (const float*)d_in[11];
  const float* kb = (const float*)d_in[12];
  const float* km = (const float*)d_in[13];
  const float* kv = (const float*)d_in[14];
  const float* vg = (const float*)d_in[15];
  const float* vb = (const float*)d_in[16];
  const float* vm = (const float*)d_in[17];
  const float* vv = (const float*)d_in[18];
  const float* og = (const float*)d_in[19];
  const float* ob = (const float*)d_in[20];
  const float* om = (const float*)d_in[21];
  const float* ov = (const float*)d_in[22];

  char* ws = (char*)d_ws;
  __bf16* xT = (__bf16*)(ws);                       // 4 MB
  __bf16* Q  = (__bf16*)(ws + (4ull << 20));        // 4 MB
  __bf16* K  = (__bf16*)(ws + (8ull << 20));        // 4 MB
  __bf16* V  = (__bf16*)(ws + (12ull << 20));       // 8 MB
  __bf16* G  = (__bf16*)(ws + (20ull << 20));       // 8 MB
  __bf16* WB = (__bf16*)(ws + (28ull << 20));       // 768 KB bf16 weights (stacked)
  float*  BB = (float*)(ws + (28ull << 20) + (768ull << 10));  // 5 KB biases
  uint2*  Tq = (uint2*)(ws + (29ull << 20));        // 128 KB bias table
  float* out = (float*)d_out;

  k_prep_trans<<<dim3(2117), 256, 0, stream>>>(
      x, Wq, Wk, Wv, Wo, bo, pe, qg, qb, qm, qv, kg, kb, km, kv,
      vg, vb, vm, vv, og, ob, om, ov, xT, WB, BB, Tq);
  // QKV: M=8192 (b,n), N=1024 stacked outs, K=256 (4 steps)
  k_gemm<<<dim3(64, 8), 256, 0, stream>>>(xT, WB, BB, Q, K, V, nullptr,
                                          DIM, 4, 0);
  k_attn<<<dim3(512), 256, 0, stream>>>(Q, K, V, Tq, G);
  // out-proj: M=8192, N=256, K=512 (8 steps)
  k_gemm<<<dim3(64, 2), 256, 0, stream>>>(G, WB + 262144, BB + 1024,
                                          nullptr, nullptr, nullptr, out,
                                          IDV, 8, 3);
}

// Round 7
// 60.643 us; speedup vs baseline: 2.8813x; 1.0482x over previous
//
#include <hip/hip_runtime.h>
#include <hip/hip_bf16.h>

#define HEADS 8
#define DK 32
#define DV 64
#define DIM 256
#define NCTX 1024
#define NB 8
#define IDK 256
#define IDV 512
#define SCALE 0.17677669529663687f
#define INV_SCALE 5.656854249492381f
#define LOG2E 1.4426950408889634f
#define BN_EPS 1e-5f
#define THR 11.5416f   /* 8 * log2e : defer-max threshold in log2 domain */

typedef __bf16 bf16x8 __attribute__((ext_vector_type(8)));
typedef __bf16 bf16x4 __attribute__((ext_vector_type(4)));
typedef float f32x4 __attribute__((ext_vector_type(4)));
typedef float f32x16 __attribute__((ext_vector_type(16)));

static __device__ __forceinline__ unsigned short bfbits(float v) {
  __bf16 b = (__bf16)v;
  return __builtin_bit_cast(unsigned short, b);
}

// ---------------- prep (weights+bias+bias-table) U transpose ----------------
// WB: stacked rows [1024][256]: WqB | WkB | WvB, then WoB[256][512]
// BB: bq[256] | bk[256] | bv[512] | bo2[256] (f32)
// Tq4g[h][t] (uint2 = 4 bf16): rr=0..3 -> pe_h[|t-rr-1023|]*INV_SCALE*LOG2E
// Q-path carries LOG2E so softmax exp becomes raw v_exp_f32 (2^x).
__global__ __launch_bounds__(256) void k_prep_trans(
    const float* __restrict__ x,
    const float* __restrict__ Wq, const float* __restrict__ Wk,
    const float* __restrict__ Wv, const float* __restrict__ Wo,
    const float* __restrict__ bo, const float* __restrict__ pe,
    const float* __restrict__ qg, const float* __restrict__ qb,
    const float* __restrict__ qm, const float* __restrict__ qv,
    const float* __restrict__ kg, const float* __restrict__ kb,
    const float* __restrict__ km, const float* __restrict__ kv,
    const float* __restrict__ vg, const float* __restrict__ vb,
    const float* __restrict__ vm, const float* __restrict__ vv,
    const float* __restrict__ og, const float* __restrict__ ob,
    const float* __restrict__ om, const float* __restrict__ ov,
    __bf16* __restrict__ xT, __bf16* __restrict__ WB, float* __restrict__ BB,
    uint2* __restrict__ Tq4g) {
  int bid = blockIdx.x;
  if (bid < 1605) {
    int idx = bid * 256 + threadIdx.x;
    if (idx < 65536) {
      int o = idx >> 8;
      WB[idx] = (__bf16)(Wq[idx] * (qg[o] * rsqrtf(qv[o] + BN_EPS) * SCALE * LOG2E));
    } else if (idx < 131072) {
      int i = idx - 65536, o = i >> 8;
      WB[idx] = (__bf16)(Wk[i] * (kg[o] * rsqrtf(kv[o] + BN_EPS)));
    } else if (idx < 262144) {
      int i = idx - 131072, o = i >> 8;
      WB[idx] = (__bf16)(Wv[i] * (vg[o] * rsqrtf(vv[o] + BN_EPS)));
    } else if (idx < 393216) {
      int i = idx - 262144, o = i >> 9;
      WB[idx] = (__bf16)(Wo[i] * (og[o] * rsqrtf(ov[o] + BN_EPS)));
    } else if (idx < 394496) {
      int i = idx - 393216;
      if (i < 256) {
        float sc = qg[i] * rsqrtf(qv[i] + BN_EPS);
        BB[i] = (qb[i] - qm[i] * sc) * SCALE * LOG2E;
      } else if (i < 512) {
        int o = i - 256;
        float sc = kg[o] * rsqrtf(kv[o] + BN_EPS);
        BB[i] = kb[o] - km[o] * sc;
      } else if (i < 1024) {
        int o = i - 512;
        float sc = vg[o] * rsqrtf(vv[o] + BN_EPS);
        BB[i] = vb[o] - vm[o] * sc;
      } else {
        int o = i - 1024;
        float sc = og[o] * rsqrtf(ov[o] + BN_EPS);
        BB[i] = (bo[o] - om[o]) * sc + ob[o];
      }
    } else {
      int i = idx - 394496;          // 8 * 2048 entries
      int h = i >> 11, t = i & 2047;
      unsigned short us[4];
#pragma unroll
      for (int rr = 0; rr < 4; ++rr) {
        int d = t - rr - 1023; d = d < 0 ? -d : d; d = d > 1023 ? 1023 : d;
        us[rr] = bfbits(pe[(size_t)d * HEADS + h] * INV_SCALE * LOG2E);
      }
      uint2 e;
      e.x = (unsigned)us[0] | ((unsigned)us[1] << 16);
      e.y = (unsigned)us[2] | ((unsigned)us[3] << 16);
      Tq4g[((size_t)h << 11) + t] = e;
    }
  } else {
    // transpose x[b,c,n] f32 -> xT[b,n,c] bf16
    __shared__ float t[64][65];
    int tb = bid - 1605;
    int b = tb >> 6, c0 = ((tb >> 4) & 3) * 64, n0 = (tb & 15) * 64;
    int col = threadIdx.x & 63, rb = threadIdx.x >> 6;
    const float* xp = x + ((size_t)b * DIM + c0) * NCTX + n0;
#pragma unroll
    for (int r = 0; r < 16; ++r) {
      int row = rb + 4 * r;
      t[row][col] = xp[(size_t)row * NCTX + col];
    }
    __syncthreads();
    __bf16* op = xT + ((size_t)b * NCTX + n0) * DIM + c0;
#pragma unroll
    for (int r = 0; r < 16; ++r) {
      int i = rb + 4 * r;
      op[(size_t)i * DIM + col] = (__bf16)t[col][i];
    }
  }
}

// ---------------- QKV GEMM: 128x128 block, XOR-swizzled LDS, packed stores ----
// mode 0: Q (swapped: m=o, n=i)  mode 1: K (swapped)  mode 2: V (natural, out [vo][n])
__global__ __launch_bounds__(256, 2) void k_gemm_qkv(
    const __bf16* __restrict__ Xsrc, const __bf16* __restrict__ Wsrc,
    const float* __restrict__ Bias, __bf16* __restrict__ Qws,
    __bf16* __restrict__ Kws, __bf16* __restrict__ Vws) {
  int bx = blockIdx.x, by = blockIdx.y;
  int mode = by < 2 ? 0 : (by < 4 ? 1 : 2);
  int tid = threadIdx.x, wave = tid >> 6, lane = tid & 63;
  int wm = wave >> 1, wn = wave & 1;
  int l16 = lane & 15, g = (lane >> 4) & 3, g4 = g * 4;
  int R0 = bx * 128;

  __shared__ __align__(16) char XTl[16384];
  __shared__ __align__(16) char WTl[16384];

  int sr = tid >> 1, sh = tid & 1;
  const __bf16* xg = Xsrc + (size_t)(R0 + sr) * DIM + sh * 32;
  const __bf16* wg = Wsrc + (size_t)(by * 128 + sr) * DIM + sh * 32;
  int wbase = sr * 128;
  int gsw[4];
#pragma unroll
  for (int q = 0; q < 4; ++q) gsw[q] = ((sh * 4 + q) ^ (sr & 7)) * 16;

  bf16x8 sx[4], sw[4];
#pragma unroll
  for (int q = 0; q < 4; ++q) {
    sx[q] = *reinterpret_cast<const bf16x8*>(xg + q * 8);
    sw[q] = *reinterpret_cast<const bf16x8*>(wg + q * 8);
  }

  f32x4 acc[4][4] = {};
  const char* Abase = (mode <= 1) ? WTl : XTl;
  const char* Bbase = (mode <= 1) ? XTl : WTl;

  for (int st = 0; st < 4; ++st) {
    __syncthreads();
#pragma unroll
    for (int q = 0; q < 4; ++q) {
      *reinterpret_cast<bf16x8*>(XTl + wbase + gsw[q]) = sx[q];
      *reinterpret_cast<bf16x8*>(WTl + wbase + gsw[q]) = sw[q];
    }
    __syncthreads();
    if (st + 1 < 4) {   // T14: next-step loads fly across compute
      const __bf16* xn = xg + (st + 1) * 64;
      const __bf16* wn_ = wg + (st + 1) * 64;
#pragma unroll
      for (int q = 0; q < 4; ++q) {
        sx[q] = *reinterpret_cast<const bf16x8*>(xn + q * 8);
        sw[q] = *reinterpret_cast<const bf16x8*>(wn_ + q * 8);
      }
    }
#pragma unroll
    for (int kc = 0; kc < 2; ++kc) {
      bf16x8 af[4], bf[4];
#pragma unroll
      for (int t = 0; t < 4; ++t) {
        int ra = wm * 64 + t * 16 + l16;
        af[t] = *reinterpret_cast<const bf16x8*>(
            Abase + ra * 128 + (((kc * 4 + g) ^ (ra & 7)) * 16));
        int rb = wn * 64 + t * 16 + l16;
        bf[t] = *reinterpret_cast<const bf16x8*>(
            Bbase + rb * 128 + (((kc * 4 + g) ^ (rb & 7)) * 16));
      }
      __builtin_amdgcn_s_setprio(1);
#pragma unroll
      for (int mt = 0; mt < 4; ++mt)
#pragma unroll
        for (int nt = 0; nt < 4; ++nt)
          acc[mt][nt] = __builtin_amdgcn_mfma_f32_16x16x32_bf16(
              af[mt], bf[nt], acc[mt][nt], 0, 0, 0);
      __builtin_amdgcn_s_setprio(0);
    }
  }

  if (mode <= 1) {  // Q/K: acc[m=o][n=i]; pack 4 consecutive d -> b64
    __bf16* OWS = (mode == 0) ? Qws : Kws;
    const float* bb = Bias + (mode == 0 ? 0 : 256);
    int oq0 = by * 128 - (mode == 1 ? 256 : 0) + wm * 64;
#pragma unroll
    for (int mt = 0; mt < 4; ++mt) {
      int oq = oq0 + mt * 16 + g4;
      float4 b4 = *reinterpret_cast<const float4*>(&bb[oq]);
      int h = oq >> 5, d0 = oq & 31;
#pragma unroll
      for (int nt = 0; nt < 4; ++nt) {
        int i = R0 + wn * 64 + nt * 16 + l16;
        int b = i >> 10, n = i & 1023;
        bf16x4 pk;
        pk[0] = (__bf16)(acc[mt][nt][0] + b4.x);
        pk[1] = (__bf16)(acc[mt][nt][1] + b4.y);
        pk[2] = (__bf16)(acc[mt][nt][2] + b4.z);
        pk[3] = (__bf16)(acc[mt][nt][3] + b4.w);
        *reinterpret_cast<bf16x4*>(
            &OWS[(((size_t)b * HEADS + h) * NCTX + n) * DK + d0]) = pk;
      }
    }
  } else {  // V: acc[m=i][n=vo]; pack 4 consecutive n -> b64
#pragma unroll
    for (int nt = 0; nt < 4; ++nt) {
      int vo = (by - 4) * 128 + wn * 64 + nt * 16 + l16;
      float bia = Bias[512 + vo];
#pragma unroll
      for (int mt = 0; mt < 4; ++mt) {
        int i0 = R0 + wm * 64 + mt * 16 + g4;
        int b = i0 >> 10, n = i0 & 1023;
        bf16x4 pk;
#pragma unroll
        for (int rr = 0; rr < 4; ++rr) pk[rr] = (__bf16)(acc[mt][nt][rr] + bia);
        *reinterpret_cast<bf16x4*>(&Vws[((size_t)b * IDV + vo) * NCTX + n]) = pk;
      }
    }
  }
}

// ---------------- out-proj GEMM: BM=128, BN=64 -> grid 256 (1 block/CU) --------
__global__ __launch_bounds__(256, 2) void k_gemm_out(
    const __bf16* __restrict__ G, const __bf16* __restrict__ WoB,
    const float* __restrict__ bo2, float* __restrict__ out) {
  int bx = blockIdx.x, by = blockIdx.y;
  int tid = threadIdx.x, wave = tid >> 6, lane = tid & 63;
  int wm = wave >> 1, wn = wave & 1;
  int l16 = lane & 15, g = (lane >> 4) & 3, g4 = g * 4;
  int R0 = bx * 128;

  __shared__ __align__(16) char XTl[16384];   // 128 rows x 64 bf16
  __shared__ __align__(16) char WTl[8192];    //  64 rows x 64 bf16

  int sr = tid >> 1, sh = tid & 1;
  const __bf16* xg = G + (size_t)(R0 + sr) * IDV + sh * 32;
  int xbase = sr * 128;
  int gsw[4];
#pragma unroll
  for (int q = 0; q < 4; ++q) gsw[q] = ((sh * 4 + q) ^ (sr & 7)) * 16;

  int wsr = tid >> 2, wq = tid & 3;
  const __bf16* wg = WoB + (size_t)(by * 64 + wsr) * IDV + wq * 16;
  int wbase = wsr * 128;
  int gswW[2];
#pragma unroll
  for (int q = 0; q < 2; ++q) gswW[q] = ((wq * 2 + q) ^ (wsr & 7)) * 16;

  bf16x8 sx[4], sw[2];
#pragma unroll
  for (int q = 0; q < 4; ++q) sx[q] = *reinterpret_cast<const bf16x8*>(xg + q * 8);
#pragma unroll
  for (int q = 0; q < 2; ++q) sw[q] = *reinterpret_cast<const bf16x8*>(wg + q * 8);

  f32x4 acc[4][2] = {};

  for (int st = 0; st < 8; ++st) {
    __syncthreads();
#pragma unroll
    for (int q = 0; q < 4; ++q) *reinterpret_cast<bf16x8*>(XTl + xbase + gsw[q]) = sx[q];
#pragma unroll
    for (int q = 0; q < 2; ++q) *reinterpret_cast<bf16x8*>(WTl + wbase + gswW[q]) = sw[q];
    __syncthreads();
    if (st + 1 < 8) {
      const __bf16* xn = xg + (st + 1) * 64;
      const __bf16* wn_ = wg + (st + 1) * 64;
#pragma unroll
      for (int q = 0; q < 4; ++q) sx[q] = *reinterpret_cast<const bf16x8*>(xn + q * 8);
#pragma unroll
      for (int q = 0; q < 2; ++q) sw[q] = *reinterpret_cast<const bf16x8*>(wn_ + q * 8);
    }
#pragma unroll
    for (int kc = 0; kc < 2; ++kc) {
      bf16x8 af[4], bf[2];
#pragma unroll
      for (int t = 0; t < 4; ++t) {
        int ra = wm * 64 + t * 16 + l16;
        af[t] = *reinterpret_cast<const bf16x8*>(
            XTl + ra * 128 + (((kc * 4 + g) ^ (ra & 7)) * 16));
      }
#pragma unroll
      for (int t = 0; t < 2; ++t) {
        int rb = wn * 32 + t * 16 + l16;
        bf[t] = *reinterpret_cast<const bf16x8*>(
            WTl + rb * 128 + (((kc * 4 + g) ^ (rb & 7)) * 16));
      }
      __builtin_amdgcn_s_setprio(1);
#pragma unroll
      for (int mt = 0; mt < 4; ++mt)
#pragma unroll
        for (int nt = 0; nt < 2; ++nt)
          acc[mt][nt] = __builtin_amdgcn_mfma_f32_16x16x32_bf16(
              af[mt], bf[nt], acc[mt][nt], 0, 0, 0);
      __builtin_amdgcn_s_setprio(0);
    }
  }
#pragma unroll
  for (int nt = 0; nt < 2; ++nt) {
    int o = by * 64 + wn * 32 + nt * 16 + l16;
    float bia = bo2[o];
#pragma unroll
    for (int mt = 0; mt < 4; ++mt) {
      int i0 = R0 + wm * 64 + mt * 16 + g4;
      int b = i0 >> 10, n = i0 & 1023;
      float4 st;
      st.x = acc[mt][nt][0] + bia;
      st.y = acc[mt][nt][1] + bia;
      st.z = acc[mt][nt][2] + bia;
      st.w = acc[mt][nt][3] + bia;
      *reinterpret_cast<float4*>(&out[((size_t)b * DIM + o) * NCTX + n]) = st;
    }
  }
}

// ---------------- attention: 64 rows/block, 2 waves, grid 1024 -----------------
// 32x32 MFMA, in-register P (cvt_pk+permlane), bf16x4 bias table, exp2 domain.
__global__ __launch_bounds__(128, 3) void k_attn(
    const __bf16* __restrict__ Qws, const __bf16* __restrict__ Kws,
    const __bf16* __restrict__ Vws, const uint2* __restrict__ Tq4g,
    __bf16* __restrict__ G) {
  int flat = blockIdx.x;                        // 0..1023
  int swz = (flat & 7) * 128 + (flat >> 3);     // XCD-aware: 128 consecutive /XCD
  int iblk = swz & 15, bh = swz >> 4;
  int b = bh >> 3, h = bh & 7;
  int tid = threadIdx.x, wave = tid >> 6, lane = tid & 63;
  int l31 = lane & 31, hi = lane >> 5;

  __shared__ __align__(16) __bf16 Klds[64][40];
  __shared__ __align__(16) __bf16 Vlds[64 * 64];
  __shared__ __align__(16) uint2 TqL[1088];

  int i0b = iblk * 64;
  {
    const uint4* tg4 = reinterpret_cast<const uint4*>(Tq4g + ((size_t)h << 11) + i0b);
    uint4* tl4 = reinterpret_cast<uint4*>(TqL);
    for (int c = tid; c < 544; c += 128) tl4[c] = tg4[c];
  }

  int i0w = i0b + wave * 32;
  int irow = i0w + l31;
  const __bf16* qbase = Qws + (size_t)bh * NCTX * DK;
  const __bf16* kbase = Kws + (size_t)bh * NCTX * DK;
  const __bf16* vbase = Vws + ((size_t)b * IDV + h * DV) * NCTX;
  bf16x8 qf0 = *reinterpret_cast<const bf16x8*>(qbase + (size_t)irow * DK + 8 * hi);
  bf16x8 qf1 = *reinterpret_cast<const bf16x8*>(qbase + (size_t)irow * DK + 16 + 8 * hi);

  // staging: 128 threads; K 2 granules, V 4 granules per thread
  int r_ = tid >> 1, s2 = (tid & 1) * 2;
  const __bf16* kgp = kbase + (size_t)r_ * DK + 8 * s2;
  const __bf16* vgp = vbase + (size_t)r_ * NCTX + 8 * s2;
  __bf16* kw0 = &Klds[r_][8 * s2];
  __bf16* kw1 = &Klds[r_][8 * (s2 + 1)];
  __bf16* vw0 = Vlds + r_ * 64 + 8 * ((s2) ^ (r_ & 7));
  __bf16* vw1 = Vlds + r_ * 64 + 8 * ((s2 + 1) ^ (r_ & 7));
  __bf16* vw2 = Vlds + r_ * 64 + 8 * ((s2 + 4) ^ (r_ & 7));
  __bf16* vw3 = Vlds + r_ * 64 + 8 * ((s2 + 5) ^ (r_ & 7));

  bf16x8 rk0 = *reinterpret_cast<const bf16x8*>(kgp);
  bf16x8 rk1 = *reinterpret_cast<const bf16x8*>(kgp + 8);
  bf16x8 rv0 = *reinterpret_cast<const bf16x8*>(vgp);
  bf16x8 rv1 = *reinterpret_cast<const bf16x8*>(vgp + 8);
  bf16x8 rv2 = *reinterpret_cast<const bf16x8*>(vgp + 32);
  bf16x8 rv3 = *reinterpret_cast<const bf16x8*>(vgp + 40);

  f32x16 acc0 = {}, acc1 = {};
  float m = -1e30f, s = 0.0f;
  int kxb = wave * 32 + l31 + 1023 - 4 * hi;
  const bf16x4* Tqp = reinterpret_cast<const bf16x4*>(TqL);

  for (int it = 0; it < 16; ++it) {
    int j0 = it * 64;
    __syncthreads();   // A: previous tile's reads done (drains prefetch)
    *reinterpret_cast<bf16x8*>(kw0) = rk0;
    *reinterpret_cast<bf16x8*>(kw1) = rk1;
    *reinterpret_cast<bf16x8*>(vw0) = rv0;
    *reinterpret_cast<bf16x8*>(vw1) = rv1;
    *reinterpret_cast<bf16x8*>(vw2) = rv2;
    *reinterpret_cast<bf16x8*>(vw3) = rv3;
    __syncthreads();   // B: tile visible
    int jn = (j0 + 64) & (NCTX - 1);
    rk0 = *reinterpret_cast<const bf16x8*>(kgp + (size_t)jn * DK);
    rk1 = *reinterpret_cast<const bf16x8*>(kgp + (size_t)jn * DK + 8);
    rv0 = *reinterpret_cast<const bf16x8*>(vgp + jn);
    rv1 = *reinterpret_cast<const bf16x8*>(vgp + jn + 8);
    rv2 = *reinterpret_cast<const bf16x8*>(vgp + jn + 32);
    rv3 = *reinterpret_cast<const bf16x8*>(vgp + jn + 40);

    float sv[32];
#pragma unroll
    for (int jg = 0; jg < 2; ++jg) {
      bf16x8 kf0 = *reinterpret_cast<const bf16x8*>(&Klds[32 * jg + l31][8 * hi]);
      bf16x8 kf1 = *reinterpret_cast<const bf16x8*>(&Klds[32 * jg + l31][16 + 8 * hi]);
      f32x16 S = {};
      __builtin_amdgcn_s_setprio(1);
      S = __builtin_amdgcn_mfma_f32_32x32x16_bf16(kf0, qf0, S, 0, 0, 0);
      S = __builtin_amdgcn_mfma_f32_32x32x16_bf16(kf1, qf1, S, 0, 0, 0);
      __builtin_amdgcn_s_setprio(0);
      int kb_ = kxb - j0 - 32 * jg;
#pragma unroll
      for (int q = 0; q < 4; ++q) {
        bf16x4 q4 = Tqp[kb_ - 8 * q];
#pragma unroll
        for (int rr = 0; rr < 4; ++rr)
          sv[jg * 16 + q * 4 + rr] = S[q * 4 + rr] + (float)q4[rr];
      }
    }
    float pmax = sv[0];
#pragma unroll
    for (int k = 1; k < 32; ++k) pmax = fmaxf(pmax, sv[k]);
    if (__any(pmax > m + THR)) {   // rare after first tile
      float mx = fmaxf(pmax, __shfl_xor(pmax, 32));
      float mnew = fmaxf(m, mx);
      float corr = __builtin_amdgcn_exp2f(m - mnew);
      s *= corr; m = mnew;
#pragma unroll
      for (int r = 0; r < 16; ++r) {
        float cv = __shfl(corr, (r & 3) + 8 * (r >> 2) + 4 * hi);
        acc0[r] *= cv; acc1[r] *= cv;
      }
    }
#pragma unroll
    for (int k = 0; k < 32; ++k) sv[k] = __builtin_amdgcn_exp2f(sv[k] - m);
    float ps = 0.0f;
#pragma unroll
    for (int k = 0; k < 32; ++k) ps += sv[k];
    s += ps;
#pragma unroll
    for (int jg = 0; jg < 2; ++jg) {
#pragma unroll
      for (int u = 0; u < 2; ++u) {
        int base = jg * 16 + 8 * u;
        unsigned we0, we1, wo0, wo1;
        asm("v_cvt_pk_bf16_f32 %0, %1, %2" : "=v"(we0) : "v"(sv[base + 0]), "v"(sv[base + 1]));
        asm("v_cvt_pk_bf16_f32 %0, %1, %2" : "=v"(we1) : "v"(sv[base + 2]), "v"(sv[base + 3]));
        asm("v_cvt_pk_bf16_f32 %0, %1, %2" : "=v"(wo0) : "v"(sv[base + 4]), "v"(sv[base + 5]));
        asm("v_cvt_pk_bf16_f32 %0, %1, %2" : "=v"(wo1) : "v"(sv[base + 6]), "v"(sv[base + 7]));
        asm volatile("v_permlane32_swap_b32 %0, %1" : "+v"(we0), "+v"(wo0));
        asm volatile("v_permlane32_swap_b32 %0, %1" : "+v"(we1), "+v"(wo1));
        uint4 pw = {we0, we1, wo0, wo1};
        bf16x8 pfrag = *reinterpret_cast<bf16x8*>(&pw);
        int c = jg * 2 + u;
        int sl = 2 * c + hi;
        bf16x8 vf0 = *reinterpret_cast<const bf16x8*>(Vlds + l31 * 64 + 8 * (sl ^ (l31 & 7)));
        bf16x8 vf1 = *reinterpret_cast<const bf16x8*>(Vlds + (32 + l31) * 64 + 8 * (sl ^ (l31 & 7)));
        __builtin_amdgcn_s_setprio(1);
        acc0 = __builtin_amdgcn_mfma_f32_32x32x16_bf16(pfrag, vf0, acc0, 0, 0, 0);
        acc1 = __builtin_amdgcn_mfma_f32_32x32x16_bf16(pfrag, vf1, acc1, 0, 0, 0);
        __builtin_amdgcn_s_setprio(0);
      }
    }
  }
  float srow = s + __shfl_xor(s, 32);
  float inv = 1.0f / srow;
  __bf16* gbase = G + (size_t)b * NCTX * IDV + h * DV + l31;
#pragma unroll
  for (int r = 0; r < 16; ++r) {
    int il = (r & 3) + 8 * (r >> 2) + 4 * hi;
    float iv = __shfl(inv, il);
    float v0 = acc0[r] * iv, v1 = acc1[r] * iv;
    float g0 = 0.5f * v0 * (1.0f + erff(v0 * 0.70710678118654752f));
    float g1 = 0.5f * v1 * (1.0f + erff(v1 * 0.70710678118654752f));
    gbase[(size_t)(i0w + il) * IDV] = (__bf16)g0;
    gbase[(size_t)(i0w + il) * IDV + 32] = (__bf16)g1;
  }
}

extern "C" void kernel_launch(void* const* d_in, const int* in_sizes, int n_in,
                              void* d_out, int out_size, void* d_ws, size_t ws_size,
                              hipStream_t stream) {
  const float* x  = (const float*)d_in[0];
  const float* Wq = (const float*)d_in[1];
  const float* Wk = (const float*)d_in[2];
  const float* Wv = (const float*)d_in[3];
  const float* Wo = (const float*)d_in[4];
  const float* bo = (const float*)d_in[5];
  const float* pe = (const float*)d_in[6];
  const float* qg = (const float*)d_in[7];
  const float* qb = (const float*)d_in[8];
  const float* qm = (const float*)d_in[9];
  const float* qv = (const float*)d_in[10];
  const float* kg = (const float*)d_in[11];
  const float* kb = (const float*)d_in[12];
  const float* km = (const float*)d_in[13];
  const float* kv = (const float*)d_in[14];
  const float* vg = (const float*)d_in[15];
  const float* vb = (const float*)d_in[16];
  const float* vm = (const float*)d_in[17];
  const float* vv = (const float*)d_in[18];
  const float* og = (const float*)d_in[19];
  const float* ob = (const float*)d_in[20];
  const float* om = (const float*)d_in[21];
  const float* ov = (const float*)d_in[22];

  char* ws = (char*)d_ws;
  __bf16* xT = (__bf16*)(ws);                       // 4 MB
  __bf16* Q  = (__bf16*)(ws + (4ull << 20));        // 4 MB
  __bf16* K  = (__bf16*)(ws + (8ull << 20));        // 4 MB
  __bf16* V  = (__bf16*)(ws + (12ull << 20));       // 8 MB
  __bf16* G  = (__bf16*)(ws + (20ull << 20));       // 8 MB
  __bf16* WB = (__bf16*)(ws + (28ull << 20));       // 768 KB bf16 weights (stacked)
  float*  BB = (float*)(ws + (28ull << 20) + (768ull << 10));  // 5 KB biases
  uint2*  Tq = (uint2*)(ws + (29ull << 20));        // 128 KB bias table
  float* out = (float*)d_out;

  k_prep_trans<<<dim3(2117), 256, 0, stream>>>(
      x, Wq, Wk, Wv, Wo, bo, pe, qg, qb, qm, qv, kg, kb, km, kv,
      vg, vb, vm, vv, og, ob, om, ov, xT, WB, BB, Tq);
  k_gemm_qkv<<<dim3(64, 8), 256, 0, stream>>>(xT, WB, BB, Q, K, V);
  k_attn<<<dim3(1024), 128, 0, stream>>>(Q, K, V, Tq, G);
  k_gemm_out<<<dim3(64, 4), 256, 0, stream>>>(G, WB + 262144, BB + 1024, out);
}